// Round 1
// baseline (1839.117 us; speedup 1.0000x reference)
//
#include <hip/hip_runtime.h>
#include <math.h>

#define NLIG 16384
#define NPROT 131072
#define NTOT (NLIG + NPROT)
#define NEDGE 2097152
#define NB 256
#define H 64

// ---------------- time embedding MLP: t (B,) -> t_emb (B, 64) ----------------
__global__ void time_mlp_kernel(const float* __restrict__ t,
                                const float* __restrict__ Wt1, const float* __restrict__ bt1,
                                const float* __restrict__ Wt2, const float* __restrict__ bt2,
                                float* __restrict__ t_emb) {
    int b = blockIdx.x;
    int h = threadIdx.x;
    __shared__ float emb_s[H];
    __shared__ float h1_s[H];
    float tv = t[b];
    int i = h & 31;
    // freqs[i] = exp(i * (-ln(10000)/31))
    float freq = expf((float)i * (-9.2103403719761836f / 31.0f));
    float e = tv * freq;
    emb_s[h] = (h < 32) ? sinf(e) : cosf(e);
    __syncthreads();
    float acc = bt1[h];
    #pragma unroll 8
    for (int k = 0; k < H; k++) acc += emb_s[k] * Wt1[k * H + h];
    float sig = 1.0f / (1.0f + expf(-acc));
    h1_s[h] = acc * sig;   // silu
    __syncthreads();
    float acc2 = bt2[h];
    #pragma unroll 8
    for (int k = 0; k < H; k++) acc2 += h1_s[k] * Wt2[k * H + h];
    t_emb[b * H + h] = acc2;
}

// ---------------- node feature init: x (N, 64) ----------------
// one wave per node, lane = feature h
__global__ void node_init_kernel(const float* __restrict__ lig_feat,
                                 const float* __restrict__ prot_feat,
                                 const int* __restrict__ lig_batch,
                                 const float* __restrict__ t_emb,
                                 const float* __restrict__ W_lig, const float* __restrict__ b_lig,
                                 const float* __restrict__ W_prot, const float* __restrict__ b_prot,
                                 float* __restrict__ x) {
    int node = blockIdx.x * 4 + (threadIdx.x >> 6);
    int h = threadIdx.x & 63;
    if (node >= NTOT) return;
    float acc;
    if (node < NLIG) {
        int b = lig_batch[node];
        acc = b_lig[h] + t_emb[b * H + h];
        #pragma unroll
        for (int k = 0; k < 15; k++)
            acc += lig_feat[node * 15 + k] * W_lig[k * H + h];
    } else {
        int p = node - NLIG;
        acc = b_prot[h];
        #pragma unroll
        for (int k = 0; k < 8; k++)
            acc += prot_feat[p * 8 + k] * W_prot[k * H + h];
    }
    x[node * H + h] = acc;
}

// ---------------- edge scatter: agg[dst] += x[src] ----------------
// one wave per edge, lane = feature h; 256B coalesced read + 256B atomic add
__global__ void scatter_kernel(const int* __restrict__ edge_index,
                               const float* __restrict__ x,
                               float* __restrict__ agg) {
    int e = blockIdx.x * 4 + (threadIdx.x >> 6);
    int h = threadIdx.x & 63;
    if (e >= NEDGE) return;
    int src = edge_index[e];
    int dst = edge_index[NEDGE + e];
    float v = x[src * H + h];
    unsafeAtomicAdd(&agg[dst * H + h], v);   // HW global_atomic_add_f32
}

// ---------------- combine: xout = agg @ Wrel + brel + x @ Wroot ----------------
// agg and xout may alias (in-place): row is fully read before being written by
// the same wave, and no other wave touches it. So no __restrict__ on those.
__global__ __launch_bounds__(256) void combine_kernel(const float* agg,
                                                      const float* __restrict__ x,
                                                      const float* __restrict__ Wrel,
                                                      const float* __restrict__ brel,
                                                      const float* __restrict__ Wroot,
                                                      float* xout) {
    __shared__ float Wrel_s[H * H];
    __shared__ float Wroot_s[H * H];
    __shared__ float brel_s[H];
    __shared__ float rowa[4][H];
    __shared__ float rowx[4][H];
    for (int i = threadIdx.x; i < H * H; i += 256) {
        Wrel_s[i] = Wrel[i];
        Wroot_s[i] = Wroot[i];
    }
    if (threadIdx.x < H) brel_s[threadIdx.x] = brel[threadIdx.x];
    __syncthreads();
    int w = threadIdx.x >> 6;
    int h = threadIdx.x & 63;
    int stride = gridDim.x * 4;
    // grid chosen so NTOT % stride == 0 -> uniform trip count, barrier-safe
    for (int node = blockIdx.x * 4 + w; node < NTOT; node += stride) {
        float a = agg[node * H + h];
        float xv = x[node * H + h];
        rowa[w][h] = a;
        rowx[w][h] = xv;
        __syncthreads();
        float acc = brel_s[h];
        #pragma unroll
        for (int k = 0; k < H; k += 4) {
            float4 av = *(const float4*)&rowa[w][k];
            float4 bv = *(const float4*)&rowx[w][k];
            acc += av.x * Wrel_s[(k + 0) * H + h] + bv.x * Wroot_s[(k + 0) * H + h];
            acc += av.y * Wrel_s[(k + 1) * H + h] + bv.y * Wroot_s[(k + 1) * H + h];
            acc += av.z * Wrel_s[(k + 2) * H + h] + bv.z * Wroot_s[(k + 2) * H + h];
            acc += av.w * Wrel_s[(k + 3) * H + h] + bv.w * Wroot_s[(k + 3) * H + h];
        }
        xout[node * H + h] = acc;
        __syncthreads();
    }
}

// ---------------- ligand pooling: pooled[b] += x[node], cnt[b] += 1 ----------------
__global__ void pool_kernel(const float* __restrict__ x,
                            const int* __restrict__ lig_batch,
                            float* __restrict__ pooled, float* __restrict__ cnt) {
    int node = blockIdx.x * 4 + (threadIdx.x >> 6);
    int h = threadIdx.x & 63;
    if (node >= NLIG) return;
    int b = lig_batch[node];
    unsafeAtomicAdd(&pooled[b * H + h], x[node * H + h]);
    if (h == 0) unsafeAtomicAdd(&cnt[b], 1.0f);
}

// ---------------- readout: out = silu(pooled/cnt @ Wro1 + bro1) @ Wro2 + bro2 ----------------
__global__ void readout_kernel(const float* __restrict__ pooled, const float* __restrict__ cnt,
                               const float* __restrict__ Wro1, const float* __restrict__ bro1,
                               const float* __restrict__ Wro2, const float* __restrict__ bro2,
                               float* __restrict__ out) {
    __shared__ float pm[4][H];
    int w = threadIdx.x >> 6;
    int h = threadIdx.x & 63;
    int b = blockIdx.x * 4 + w;
    float c = fmaxf(cnt[b], 1.0f);
    pm[w][h] = pooled[b * H + h] / c;
    __syncthreads();
    float acc = bro1[h];
    #pragma unroll 8
    for (int k = 0; k < H; k++) acc += pm[w][k] * Wro1[k * H + h];
    float sig = 1.0f / (1.0f + expf(-acc));
    float s = acc * sig;
    float r = s * Wro2[h];
    #pragma unroll
    for (int off = 32; off; off >>= 1) r += __shfl_down(r, off);
    if (h == 0) out[b] = r + bro2[0];
}

extern "C" void kernel_launch(void* const* d_in, const int* in_sizes, int n_in,
                              void* d_out, int out_size, void* d_ws, size_t ws_size,
                              hipStream_t stream) {
    const float* lig_feat  = (const float*)d_in[1];
    const float* prot_feat = (const float*)d_in[3];
    const float* t         = (const float*)d_in[4];
    const int*   lig_batch = (const int*)d_in[5];
    const int*   edge_index= (const int*)d_in[7];
    const float* W_lig  = (const float*)d_in[8];
    const float* b_lig  = (const float*)d_in[9];
    const float* W_prot = (const float*)d_in[10];
    const float* b_prot = (const float*)d_in[11];
    const float* Wt1 = (const float*)d_in[12];
    const float* bt1 = (const float*)d_in[13];
    const float* Wt2 = (const float*)d_in[14];
    const float* bt2 = (const float*)d_in[15];
    const float* Wrel[3]  = {(const float*)d_in[16], (const float*)d_in[19], (const float*)d_in[22]};
    const float* brel[3]  = {(const float*)d_in[17], (const float*)d_in[20], (const float*)d_in[23]};
    const float* Wroot[3] = {(const float*)d_in[18], (const float*)d_in[21], (const float*)d_in[24]};
    const float* Wro1 = (const float*)d_in[25];
    const float* bro1 = (const float*)d_in[26];
    const float* Wro2 = (const float*)d_in[27];
    const float* bro2 = (const float*)d_in[28];
    float* out = (float*)d_out;

    char* ws = (char*)d_ws;
    float* t_emb  = (float*)(ws);               // 64 KiB
    float* pooled = (float*)(ws + 65536);       // 64 KiB
    float* cnt    = (float*)(ws + 131072);      // 1 KiB
    size_t xbytes = (size_t)NTOT * H * sizeof(float);  // 37,748,736 B
    float* buf0 = (float*)(ws + (1 << 20));
    float* buf1 = (float*)(ws + (1 << 20) + xbytes);
    float* bufs[2] = {buf0, buf1};

    time_mlp_kernel<<<NB, H, 0, stream>>>(t, Wt1, bt1, Wt2, bt2, t_emb);

    node_init_kernel<<<NTOT / 4, 256, 0, stream>>>(lig_feat, prot_feat, lig_batch, t_emb,
                                                   W_lig, b_lig, W_prot, b_prot, buf0);

    for (int l = 0; l < 3; l++) {
        float* cur = bufs[l & 1];        // x input
        float* nxt = bufs[(l + 1) & 1];  // agg, then overwritten in-place with x_out
        hipMemsetAsync(nxt, 0, xbytes, stream);
        scatter_kernel<<<NEDGE / 4, 256, 0, stream>>>(edge_index, cur, nxt);
        combine_kernel<<<2048, 256, 0, stream>>>(nxt, cur, Wrel[l], brel[l], Wroot[l], nxt);
    }
    // final x lives in bufs[1] after 3 convs (0->1, 1->0, 0->1)
    float* xfin = bufs[1];

    hipMemsetAsync(pooled, 0, (size_t)(NB * H + NB) * sizeof(float), stream);
    pool_kernel<<<NLIG / 4, 256, 0, stream>>>(xfin, lig_batch, pooled, cnt);
    readout_kernel<<<NB / 4, 256, 0, stream>>>(pooled, cnt, Wro1, bro1, Wro2, bro2, out);
}

// Round 2
// 887.001 us; speedup vs baseline: 2.0734x; 2.0734x over previous
//
#include <hip/hip_runtime.h>
#include <math.h>

#define NLIG 16384
#define NPROT 131072
#define NTOT (NLIG + NPROT)
#define NEDGE 2097152
#define NB 256
#define H 64

// ---------------- time embedding MLP: t (B,) -> t_emb (B, 64) ----------------
__global__ void time_mlp_kernel(const float* __restrict__ t,
                                const float* __restrict__ Wt1, const float* __restrict__ bt1,
                                const float* __restrict__ Wt2, const float* __restrict__ bt2,
                                float* __restrict__ t_emb) {
    int b = blockIdx.x;
    int h = threadIdx.x;
    __shared__ float emb_s[H];
    __shared__ float h1_s[H];
    float tv = t[b];
    int i = h & 31;
    float freq = expf((float)i * (-9.2103403719761836f / 31.0f));
    float e = tv * freq;
    emb_s[h] = (h < 32) ? sinf(e) : cosf(e);
    __syncthreads();
    float acc = bt1[h];
    #pragma unroll 8
    for (int k = 0; k < H; k++) acc += emb_s[k] * Wt1[k * H + h];
    float sig = 1.0f / (1.0f + expf(-acc));
    h1_s[h] = acc * sig;   // silu
    __syncthreads();
    float acc2 = bt2[h];
    #pragma unroll 8
    for (int k = 0; k < H; k++) acc2 += h1_s[k] * Wt2[k * H + h];
    t_emb[b * H + h] = acc2;
}

// ---------------- node feature init: x (N, 64) ----------------
__global__ void node_init_kernel(const float* __restrict__ lig_feat,
                                 const float* __restrict__ prot_feat,
                                 const int* __restrict__ lig_batch,
                                 const float* __restrict__ t_emb,
                                 const float* __restrict__ W_lig, const float* __restrict__ b_lig,
                                 const float* __restrict__ W_prot, const float* __restrict__ b_prot,
                                 float* __restrict__ x) {
    int node = blockIdx.x * 4 + (threadIdx.x >> 6);
    int h = threadIdx.x & 63;
    if (node >= NTOT) return;
    float acc;
    if (node < NLIG) {
        int b = lig_batch[node];
        acc = b_lig[h] + t_emb[b * H + h];
        #pragma unroll
        for (int k = 0; k < 15; k++)
            acc += lig_feat[node * 15 + k] * W_lig[k * H + h];
    } else {
        int p = node - NLIG;
        acc = b_prot[h];
        #pragma unroll
        for (int k = 0; k < 8; k++)
            acc += prot_feat[p * 8 + k] * W_prot[k * H + h];
    }
    x[node * H + h] = acc;
}

// ---------------- CSR build ----------------
// hist: deg[dst]++ over all edges (deg stored in `off` array)
__global__ void hist_kernel(const int* __restrict__ edge_index, int* __restrict__ off) {
    int e = blockIdx.x * 256 + threadIdx.x;
    if (e >= NEDGE) return;
    atomicAdd(&off[edge_index[NEDGE + e]], 1);
}

// scan1: per-block (256-wide) exclusive scan in place; block totals to bsum
__global__ void scan1_kernel(int* __restrict__ data, int* __restrict__ bsum) {
    __shared__ int s[256];
    int tid = threadIdx.x;
    int i = blockIdx.x * 256 + tid;
    s[tid] = data[i];
    __syncthreads();
    for (int d = 1; d < 256; d <<= 1) {
        int v = (tid >= d) ? s[tid - d] : 0;
        __syncthreads();
        s[tid] += v;
        __syncthreads();
    }
    data[i] = tid ? s[tid - 1] : 0;
    if (tid == 255) bsum[blockIdx.x] = s[255];
}

// scan2: exclusive scan of the 576 block sums (single block of 1024)
__global__ void scan2_kernel(int* __restrict__ bsum, int nblk) {
    __shared__ int s[1024];
    int tid = threadIdx.x;
    s[tid] = (tid < nblk) ? bsum[tid] : 0;
    __syncthreads();
    for (int d = 1; d < 1024; d <<= 1) {
        int v = (tid >= d) ? s[tid - d] : 0;
        __syncthreads();
        s[tid] += v;
        __syncthreads();
    }
    if (tid < nblk) bsum[tid] = tid ? s[tid - 1] : 0;
}

// scan3: add block offsets; init cursor; set off[NTOT]
__global__ void scan3_kernel(int* __restrict__ off, const int* __restrict__ bsum,
                             int* __restrict__ cursor) {
    int i = blockIdx.x * 256 + threadIdx.x;
    int v = off[i] + bsum[blockIdx.x];
    off[i] = v;
    cursor[i] = v;
    if (i == 0) off[NTOT] = NEDGE;
}

// fill: csr_src[pos] = src, pos = cursor[dst]++
__global__ void fill_kernel(const int* __restrict__ edge_index,
                            int* __restrict__ cursor, int* __restrict__ csr_src) {
    int e = blockIdx.x * 256 + threadIdx.x;
    if (e >= NEDGE) return;
    int src = edge_index[e];
    int dst = edge_index[NEDGE + e];
    int pos = atomicAdd(&cursor[dst], 1);
    csr_src[pos] = src;
}

// ---------------- fused conv: xout = (sum_{src in N(dst)} x[src]) @ Wrel + brel + x @ Wroot ----------------
// one wave per dst node; lane = feature h. Weights held in VGPRs (128 regs),
// row broadcast via v_readlane -> no atomics, no LDS, no barriers.
__global__ __launch_bounds__(256) void conv_kernel(const int* __restrict__ off,
                                                   const int* __restrict__ csr_src,
                                                   const float* __restrict__ x,
                                                   const float* __restrict__ Wrel,
                                                   const float* __restrict__ brel,
                                                   const float* __restrict__ Wroot,
                                                   float* __restrict__ xout) {
    const int w = threadIdx.x >> 6;
    const int h = threadIdx.x & 63;
    float wrel[H], wroot[H];
    #pragma unroll
    for (int k = 0; k < H; k++) {
        wrel[k]  = Wrel[k * H + h];
        wroot[k] = Wroot[k * H + h];
    }
    const float br = brel[h];
    const int stride = gridDim.x * 4;
    for (int node = blockIdx.x * 4 + w; node < NTOT; node += stride) {
        int beg = off[node];
        int end = off[node + 1];
        float acc = 0.0f;
        for (int j0 = beg; j0 < end; j0 += 64) {
            int cnt = end - j0;
            if (cnt > 64) cnt = 64;
            int id = (j0 + h < end) ? csr_src[j0 + h] : 0;
            int j = 0;
            for (; j + 3 < cnt; j += 4) {
                int s0 = __shfl(id, j);
                int s1 = __shfl(id, j + 1);
                int s2 = __shfl(id, j + 2);
                int s3 = __shfl(id, j + 3);
                float v0 = x[s0 * H + h];
                float v1 = x[s1 * H + h];
                float v2 = x[s2 * H + h];
                float v3 = x[s3 * H + h];
                acc += (v0 + v1) + (v2 + v3);
            }
            for (; j < cnt; j++) acc += x[__shfl(id, j) * H + h];
        }
        float xv = x[node * H + h];
        float out = br;
        #pragma unroll
        for (int k = 0; k < H; k++) {
            float ak = __uint_as_float(__builtin_amdgcn_readlane(__float_as_uint(acc), k));
            float xk = __uint_as_float(__builtin_amdgcn_readlane(__float_as_uint(xv), k));
            out = fmaf(ak, wrel[k], out);
            out = fmaf(xk, wroot[k], out);
        }
        xout[node * H + h] = out;
    }
}

// ---------------- ligand pooling ----------------
__global__ void pool_kernel(const float* __restrict__ x,
                            const int* __restrict__ lig_batch,
                            float* __restrict__ pooled, float* __restrict__ cnt) {
    int node = blockIdx.x * 4 + (threadIdx.x >> 6);
    int h = threadIdx.x & 63;
    if (node >= NLIG) return;
    int b = lig_batch[node];
    unsafeAtomicAdd(&pooled[b * H + h], x[node * H + h]);
    if (h == 0) unsafeAtomicAdd(&cnt[b], 1.0f);
}

// ---------------- readout ----------------
__global__ void readout_kernel(const float* __restrict__ pooled, const float* __restrict__ cnt,
                               const float* __restrict__ Wro1, const float* __restrict__ bro1,
                               const float* __restrict__ Wro2, const float* __restrict__ bro2,
                               float* __restrict__ out) {
    __shared__ float pm[4][H];
    int w = threadIdx.x >> 6;
    int h = threadIdx.x & 63;
    int b = blockIdx.x * 4 + w;
    float c = fmaxf(cnt[b], 1.0f);
    pm[w][h] = pooled[b * H + h] / c;
    __syncthreads();
    float acc = bro1[h];
    #pragma unroll 8
    for (int k = 0; k < H; k++) acc += pm[w][k] * Wro1[k * H + h];
    float sig = 1.0f / (1.0f + expf(-acc));
    float s = acc * sig;
    float r = s * Wro2[h];
    #pragma unroll
    for (int off = 32; off; off >>= 1) r += __shfl_down(r, off);
    if (h == 0) out[b] = r + bro2[0];
}

extern "C" void kernel_launch(void* const* d_in, const int* in_sizes, int n_in,
                              void* d_out, int out_size, void* d_ws, size_t ws_size,
                              hipStream_t stream) {
    const float* lig_feat  = (const float*)d_in[1];
    const float* prot_feat = (const float*)d_in[3];
    const float* t         = (const float*)d_in[4];
    const int*   lig_batch = (const int*)d_in[5];
    const int*   edge_index= (const int*)d_in[7];
    const float* W_lig  = (const float*)d_in[8];
    const float* b_lig  = (const float*)d_in[9];
    const float* W_prot = (const float*)d_in[10];
    const float* b_prot = (const float*)d_in[11];
    const float* Wt1 = (const float*)d_in[12];
    const float* bt1 = (const float*)d_in[13];
    const float* Wt2 = (const float*)d_in[14];
    const float* bt2 = (const float*)d_in[15];
    const float* Wrel[3]  = {(const float*)d_in[16], (const float*)d_in[19], (const float*)d_in[22]};
    const float* brel[3]  = {(const float*)d_in[17], (const float*)d_in[20], (const float*)d_in[23]};
    const float* Wroot[3] = {(const float*)d_in[18], (const float*)d_in[21], (const float*)d_in[24]};
    const float* Wro1 = (const float*)d_in[25];
    const float* bro1 = (const float*)d_in[26];
    const float* Wro2 = (const float*)d_in[27];
    const float* bro2 = (const float*)d_in[28];
    float* out = (float*)d_out;

    char* ws = (char*)d_ws;
    int*   off_a   = (int*)(ws);                       // (NTOT+1) ints
    int*   cursor  = (int*)(ws + 655360);              // NTOT ints
    int*   bsum    = (int*)(ws + 1310720);             // 576 ints
    float* t_emb   = (float*)(ws + 1376256);           // 64 KiB
    float* pooled  = (float*)(ws + 1441792);           // 64 KiB
    float* cnt     = (float*)(ws + 1507328);           // 1 KiB
    int*   csr_src = (int*)(ws + 2097152);             // 8 MiB
    size_t xbytes  = (size_t)NTOT * H * sizeof(float); // 37,748,736
    float* buf0 = (float*)(ws + 10485760);
    float* buf1 = (float*)(ws + 10485760 + xbytes);
    float* bufs[2] = {buf0, buf1};

    time_mlp_kernel<<<NB, H, 0, stream>>>(t, Wt1, bt1, Wt2, bt2, t_emb);
    node_init_kernel<<<NTOT / 4, 256, 0, stream>>>(lig_feat, prot_feat, lig_batch, t_emb,
                                                   W_lig, b_lig, W_prot, b_prot, buf0);

    // ---- CSR build (once, reused by all 3 convs) ----
    hipMemsetAsync(off_a, 0, (size_t)(NTOT + 1) * sizeof(int), stream);
    hist_kernel<<<NEDGE / 256, 256, 0, stream>>>(edge_index, off_a);
    scan1_kernel<<<NTOT / 256, 256, 0, stream>>>(off_a, bsum);
    scan2_kernel<<<1, 1024, 0, stream>>>(bsum, NTOT / 256);
    scan3_kernel<<<NTOT / 256, 256, 0, stream>>>(off_a, bsum, cursor);
    fill_kernel<<<NEDGE / 256, 256, 0, stream>>>(edge_index, cursor, csr_src);

    // ---- 3 fused graph convs (gather + GEMM, no atomics) ----
    for (int l = 0; l < 3; l++) {
        float* cur = bufs[l & 1];
        float* nxt = bufs[(l + 1) & 1];
        conv_kernel<<<2304, 256, 0, stream>>>(off_a, csr_src, cur, Wrel[l], brel[l], Wroot[l], nxt);
    }
    float* xfin = bufs[1];

    hipMemsetAsync(pooled, 0, (size_t)(NB * H + NB) * sizeof(float), stream);
    pool_kernel<<<NLIG / 4, 256, 0, stream>>>(xfin, lig_batch, pooled, cnt);
    readout_kernel<<<NB / 4, 256, 0, stream>>>(pooled, cnt, Wro1, bro1, Wro2, bro2, out);
}

// Round 3
// 846.670 us; speedup vs baseline: 2.1722x; 1.0476x over previous
//
#include <hip/hip_runtime.h>
#include <math.h>

#define NLIG 16384
#define NPROT 131072
#define NTOT (NLIG + NPROT)
#define NEDGE 2097152
#define NB 256
#define H 64

typedef short v4s __attribute__((ext_vector_type(4)));
typedef float v4f __attribute__((ext_vector_type(4)));

__device__ __forceinline__ unsigned short f2bf(float f) {
    unsigned int u = __float_as_uint(f);
    u += 0x7fff + ((u >> 16) & 1);   // RNE
    return (unsigned short)(u >> 16);
}
__device__ __forceinline__ float bf2f(unsigned short s) {
    return __uint_as_float(((unsigned int)s) << 16);
}

// ---------------- time embedding MLP ----------------
__global__ void time_mlp_kernel(const float* __restrict__ t,
                                const float* __restrict__ Wt1, const float* __restrict__ bt1,
                                const float* __restrict__ Wt2, const float* __restrict__ bt2,
                                float* __restrict__ t_emb) {
    int b = blockIdx.x;
    int h = threadIdx.x;
    __shared__ float emb_s[H];
    __shared__ float h1_s[H];
    float tv = t[b];
    int i = h & 31;
    float freq = expf((float)i * (-9.2103403719761836f / 31.0f));
    float e = tv * freq;
    emb_s[h] = (h < 32) ? sinf(e) : cosf(e);
    __syncthreads();
    float acc = bt1[h];
    #pragma unroll 8
    for (int k = 0; k < H; k++) acc += emb_s[k] * Wt1[k * H + h];
    float sig = 1.0f / (1.0f + expf(-acc));
    h1_s[h] = acc * sig;
    __syncthreads();
    float acc2 = bt2[h];
    #pragma unroll 8
    for (int k = 0; k < H; k++) acc2 += h1_s[k] * Wt2[k * H + h];
    t_emb[b * H + h] = acc2;
}

// ---------------- weight pre-swizzle into MFMA B-fragment order (bf16) ----------------
// For 16x16x16 bf16 MFMA: B-frag lane l, elem i holds B[k=16*kt+4*(l>>4)+i][col=16*ct+(l&15)]
// Layout: wbuf[m*4096 + f*256 + l*4 + i], f = kt*4+ct
__global__ void wswz_kernel(const float* __restrict__ W0, const float* __restrict__ W1,
                            const float* __restrict__ W2, const float* __restrict__ W3,
                            const float* __restrict__ W4, const float* __restrict__ W5,
                            unsigned short* __restrict__ wbuf) {
    const float* Ws[6] = {W0, W1, W2, W3, W4, W5};
    int m = blockIdx.y;
    int t = blockIdx.x * 256 + threadIdx.x;   // 0..4095
    int f = t >> 8, l = (t >> 2) & 63, i = t & 3;
    int kt = f >> 2, ct = f & 3;
    int row = 16 * kt + 4 * (l >> 4) + i;
    int col = 16 * ct + (l & 15);
    wbuf[m * 4096 + t] = f2bf(Ws[m][row * H + col]);
}

// ---------------- node feature init -> bf16-packed x ----------------
__global__ void node_init_kernel(const float* __restrict__ lig_feat,
                                 const float* __restrict__ prot_feat,
                                 const int* __restrict__ lig_batch,
                                 const float* __restrict__ t_emb,
                                 const float* __restrict__ W_lig, const float* __restrict__ b_lig,
                                 const float* __restrict__ W_prot, const float* __restrict__ b_prot,
                                 unsigned int* __restrict__ xb) {
    int node = blockIdx.x * 4 + (threadIdx.x >> 6);
    int h = threadIdx.x & 63;
    if (node >= NTOT) return;
    float acc;
    if (node < NLIG) {
        int b = lig_batch[node];
        acc = b_lig[h] + t_emb[b * H + h];
        #pragma unroll
        for (int k = 0; k < 15; k++)
            acc += lig_feat[node * 15 + k] * W_lig[k * H + h];
    } else {
        int p = node - NLIG;
        acc = b_prot[h];
        #pragma unroll
        for (int k = 0; k < 8; k++)
            acc += prot_feat[p * 8 + k] * W_prot[k * H + h];
    }
    // pack pairs: lane c<32 stores features {2c, 2c+1}
    float e0 = __shfl(acc, 2 * (h & 31));
    float e1 = __shfl(acc, 2 * (h & 31) + 1);
    if (h < 32)
        xb[node * 32 + h] = (unsigned int)f2bf(e0) | ((unsigned int)f2bf(e1) << 16);
}

// ---------------- CSR build ----------------
__global__ void hist_kernel(const int* __restrict__ edge_index, int* __restrict__ off) {
    int e = blockIdx.x * 256 + threadIdx.x;
    if (e >= NEDGE) return;
    atomicAdd(&off[edge_index[NEDGE + e]], 1);
}

__global__ void scan1_kernel(int* __restrict__ data, int* __restrict__ bsum) {
    __shared__ int s[256];
    int tid = threadIdx.x;
    int i = blockIdx.x * 256 + tid;
    s[tid] = data[i];
    __syncthreads();
    for (int d = 1; d < 256; d <<= 1) {
        int v = (tid >= d) ? s[tid - d] : 0;
        __syncthreads();
        s[tid] += v;
        __syncthreads();
    }
    data[i] = tid ? s[tid - 1] : 0;
    if (tid == 255) bsum[blockIdx.x] = s[255];
}

__global__ void scan2_kernel(int* __restrict__ bsum, int nblk) {
    __shared__ int s[1024];
    int tid = threadIdx.x;
    s[tid] = (tid < nblk) ? bsum[tid] : 0;
    __syncthreads();
    for (int d = 1; d < 1024; d <<= 1) {
        int v = (tid >= d) ? s[tid - d] : 0;
        __syncthreads();
        s[tid] += v;
        __syncthreads();
    }
    if (tid < nblk) bsum[tid] = tid ? s[tid - 1] : 0;
}

__global__ void scan3_kernel(int* __restrict__ off, const int* __restrict__ bsum,
                             int* __restrict__ cursor) {
    int i = blockIdx.x * 256 + threadIdx.x;
    int v = off[i] + bsum[blockIdx.x];
    off[i] = v;
    cursor[i] = v;
    if (i == 0) off[NTOT] = NEDGE;
}

__global__ void fill_kernel(const int* __restrict__ edge_index,
                            int* __restrict__ cursor, int* __restrict__ csr_src) {
    int e = blockIdx.x * 256 + threadIdx.x;
    if (e >= NEDGE) return;
    int src = edge_index[e];
    int dst = edge_index[NEDGE + e];
    int pos = atomicAdd(&cursor[dst], 1);
    csr_src[pos] = src;
}

// ---------------- fused conv: gather (bf16) + MFMA combine ----------------
// One block = 64-node tile. Wave w owns nodes [16w,16w+16) of the tile.
// Phase 1: gather-sum neighbor bf16 rows (2 per iter via lane halves) -> AGG LDS tile
//          + stage own x rows -> X LDS tile. (wave-local rows: no barrier needed)
// Phase 2: MFMA: C = AGG@Wrel + X@Wroot + brel, 16x16x16 bf16 MFMAs.
// Phase 3: epilogue via LDS redistribution -> coalesced bf16 row writes.
__global__ __launch_bounds__(256) void conv_kernel(const int* __restrict__ off,
                                                   const int* __restrict__ csr,
                                                   const unsigned int* __restrict__ xb,
                                                   const unsigned short* __restrict__ wbuf,
                                                   const float* __restrict__ brel,
                                                   unsigned int* __restrict__ xob) {
    __shared__ unsigned int wlds[4096];            // 16 KB: rel frags [0,2048), root [2048,4096)
    __shared__ unsigned short agg_s[64 * 72];      // padded rows: 2-way banks only
    __shared__ unsigned short xs_s[64 * 72];
    const int tid = threadIdx.x;
    const int w = tid >> 6, l = tid & 63;
    const int node0 = blockIdx.x * 64;
    const unsigned int* wsrc = (const unsigned int*)wbuf;
    for (int i = tid; i < 4096; i += 256) wlds[i] = wsrc[i];
    __syncthreads();

    const int half = l >> 5, c = l & 31;
    // ---- gather phase ----
    for (int i = 0; i < 16; i++) {
        int ln = w * 16 + i;
        int node = node0 + ln;
        int beg = off[node], end = off[node + 1];
        float a0 = 0.f, a1 = 0.f;
        for (int j0 = beg; j0 < end; j0 += 64) {
            int cnt = end - j0; if (cnt > 64) cnt = 64;
            int id = (j0 + l < end) ? csr[j0 + l] : 0;
            int j = 0;
            for (; j + 1 < cnt; j += 2) {
                int nb = __shfl(id, j + half);       // lane half 0 -> nbr j, half 1 -> nbr j+1
                unsigned int u = xb[nb * 32 + c];
                a0 += bf2f((unsigned short)(u & 0xffffu));
                a1 += bf2f((unsigned short)(u >> 16));
            }
            if (j < cnt) {                            // odd tail
                int nb = __shfl(id, j);
                if (half == 0) {
                    unsigned int u = xb[nb * 32 + c];
                    a0 += bf2f((unsigned short)(u & 0xffffu));
                    a1 += bf2f((unsigned short)(u >> 16));
                }
            }
        }
        a0 += __shfl_xor(a0, 32);
        a1 += __shfl_xor(a1, 32);
        if (half == 0)
            *(unsigned int*)&agg_s[ln * 72 + 2 * c] =
                (unsigned int)f2bf(a0) | ((unsigned int)f2bf(a1) << 16);
    }
    // ---- stage own x rows (coalesced) ----
    #pragma unroll
    for (int i2 = 0; i2 < 8; i2++) {
        int r = w * 16 + i2 * 2 + half;
        *(unsigned int*)&xs_s[r * 72 + 2 * c] = xb[(node0 + r) * 32 + c];
    }
    // ---- MFMA phase (reads only this wave's own rows) ----
    v4f acc[4];
    #pragma unroll
    for (int ct = 0; ct < 4; ct++) acc[ct] = (v4f){0.f, 0.f, 0.f, 0.f};
    const int arow = w * 16 + (l & 15);
    const int g4 = 4 * (l >> 4);
    #pragma unroll
    for (int kt = 0; kt < 4; kt++) {
        v4s a_agg = *(const v4s*)&agg_s[arow * 72 + kt * 16 + g4];
        v4s a_x   = *(const v4s*)&xs_s [arow * 72 + kt * 16 + g4];
        #pragma unroll
        for (int ct = 0; ct < 4; ct++) {
            int f = kt * 4 + ct;
            v4s wr = *(const v4s*)&wlds[f * 128 + l * 2];
            v4s wo = *(const v4s*)&wlds[2048 + f * 128 + l * 2];
            acc[ct] = __builtin_amdgcn_mfma_f32_16x16x16bf16_1k(a_agg, wr, acc[ct], 0, 0, 0);
            acc[ct] = __builtin_amdgcn_mfma_f32_16x16x16bf16_1k(a_x,   wo, acc[ct], 0, 0, 0);
        }
    }
    // ---- epilogue: D[row=4*(l>>4)+r][col=16ct+(l&15)] -> LDS (own rows) ----
    #pragma unroll
    for (int ct = 0; ct < 4; ct++) {
        float bv = brel[ct * 16 + (l & 15)];
        #pragma unroll
        for (int r = 0; r < 4; r++)
            xs_s[(w * 16 + g4 + r) * 72 + ct * 16 + (l & 15)] = f2bf(acc[ct][r] + bv);
    }
    __syncthreads();
    // coalesced writeout: 64 rows x 32 dwords
    {
        int row = tid >> 2, q = tid & 3;
        const unsigned int* src = (const unsigned int*)&xs_s[row * 72 + q * 16];
        uint4 v0 = *(const uint4*)(src);
        uint4 v1 = *(const uint4*)(src + 4);
        *(uint4*)&xob[(node0 + row) * 32 + q * 8] = v0;
        *(uint4*)&xob[(node0 + row) * 32 + q * 8 + 4] = v1;
    }
}

// ---------------- ligand pooling (bf16 x) ----------------
__global__ void pool_kernel(const unsigned int* __restrict__ xb,
                            const int* __restrict__ lig_batch,
                            float* __restrict__ pooled, float* __restrict__ cnt) {
    int node = blockIdx.x * 4 + (threadIdx.x >> 6);
    int h = threadIdx.x & 63;
    if (node >= NLIG) return;
    int b = lig_batch[node];
    unsigned int u = xb[node * 32 + (h >> 1)];
    float v = bf2f((unsigned short)((h & 1) ? (u >> 16) : (u & 0xffffu)));
    unsafeAtomicAdd(&pooled[b * H + h], v);
    if (h == 0) unsafeAtomicAdd(&cnt[b], 1.0f);
}

// ---------------- readout ----------------
__global__ void readout_kernel(const float* __restrict__ pooled, const float* __restrict__ cnt,
                               const float* __restrict__ Wro1, const float* __restrict__ bro1,
                               const float* __restrict__ Wro2, const float* __restrict__ bro2,
                               float* __restrict__ out) {
    __shared__ float pm[4][H];
    int w = threadIdx.x >> 6;
    int h = threadIdx.x & 63;
    int b = blockIdx.x * 4 + w;
    float c = fmaxf(cnt[b], 1.0f);
    pm[w][h] = pooled[b * H + h] / c;
    __syncthreads();
    float acc = bro1[h];
    #pragma unroll 8
    for (int k = 0; k < H; k++) acc += pm[w][k] * Wro1[k * H + h];
    float sig = 1.0f / (1.0f + expf(-acc));
    float s = acc * sig;
    float r = s * Wro2[h];
    #pragma unroll
    for (int off = 32; off; off >>= 1) r += __shfl_down(r, off);
    if (h == 0) out[b] = r + bro2[0];
}

extern "C" void kernel_launch(void* const* d_in, const int* in_sizes, int n_in,
                              void* d_out, int out_size, void* d_ws, size_t ws_size,
                              hipStream_t stream) {
    const float* lig_feat  = (const float*)d_in[1];
    const float* prot_feat = (const float*)d_in[3];
    const float* t         = (const float*)d_in[4];
    const int*   lig_batch = (const int*)d_in[5];
    const int*   edge_index= (const int*)d_in[7];
    const float* W_lig  = (const float*)d_in[8];
    const float* b_lig  = (const float*)d_in[9];
    const float* W_prot = (const float*)d_in[10];
    const float* b_prot = (const float*)d_in[11];
    const float* Wt1 = (const float*)d_in[12];
    const float* bt1 = (const float*)d_in[13];
    const float* Wt2 = (const float*)d_in[14];
    const float* bt2 = (const float*)d_in[15];
    const float* Wrel[3]  = {(const float*)d_in[16], (const float*)d_in[19], (const float*)d_in[22]};
    const float* brel[3]  = {(const float*)d_in[17], (const float*)d_in[20], (const float*)d_in[23]};
    const float* Wroot[3] = {(const float*)d_in[18], (const float*)d_in[21], (const float*)d_in[24]};
    const float* Wro1 = (const float*)d_in[25];
    const float* bro1 = (const float*)d_in[26];
    const float* Wro2 = (const float*)d_in[27];
    const float* bro2 = (const float*)d_in[28];
    float* out = (float*)d_out;

    char* ws = (char*)d_ws;
    int*            off_a   = (int*)(ws);                       // (NTOT+1) ints
    int*            cursor  = (int*)(ws + 655360);
    int*            bsum    = (int*)(ws + 1310720);
    float*          t_emb   = (float*)(ws + 1376256);
    float*          pooled  = (float*)(ws + 1441792);
    float*          cnt     = (float*)(ws + 1507328);
    unsigned short* wbuf    = (unsigned short*)(ws + 1572864);  // 48 KB (6 x 4096 bf16)
    int*            csr_src = (int*)(ws + 2097152);             // 8 MB
    unsigned int*   xb0     = (unsigned int*)(ws + 10485760);   // 18 MB bf16-packed
    unsigned int*   xb1     = (unsigned int*)(ws + 29360128);   // 18 MB
    unsigned int*   xbs[2]  = {xb0, xb1};

    time_mlp_kernel<<<NB, H, 0, stream>>>(t, Wt1, bt1, Wt2, bt2, t_emb);
    wswz_kernel<<<dim3(16, 6), 256, 0, stream>>>(Wrel[0], Wroot[0], Wrel[1], Wroot[1],
                                                 Wrel[2], Wroot[2], wbuf);
    node_init_kernel<<<NTOT / 4, 256, 0, stream>>>(lig_feat, prot_feat, lig_batch, t_emb,
                                                   W_lig, b_lig, W_prot, b_prot, xb0);

    // ---- CSR build ----
    hipMemsetAsync(off_a, 0, (size_t)(NTOT + 1) * sizeof(int), stream);
    hist_kernel<<<NEDGE / 256, 256, 0, stream>>>(edge_index, off_a);
    scan1_kernel<<<NTOT / 256, 256, 0, stream>>>(off_a, bsum);
    scan2_kernel<<<1, 1024, 0, stream>>>(bsum, NTOT / 256);
    scan3_kernel<<<NTOT / 256, 256, 0, stream>>>(off_a, bsum, cursor);
    fill_kernel<<<NEDGE / 256, 256, 0, stream>>>(edge_index, cursor, csr_src);

    // ---- 3 fused graph convs ----
    for (int lyr = 0; lyr < 3; lyr++) {
        unsigned int* cur = xbs[lyr & 1];
        unsigned int* nxt = xbs[(lyr + 1) & 1];
        conv_kernel<<<NTOT / 64, 256, 0, stream>>>(off_a, csr_src, cur,
                                                   wbuf + lyr * 8192, brel[lyr], nxt);
    }
    unsigned int* xfin = xbs[1];

    hipMemsetAsync(pooled, 0, (size_t)(NB * H + NB) * sizeof(float), stream);
    pool_kernel<<<NLIG / 4, 256, 0, stream>>>(xfin, lig_batch, pooled, cnt);
    readout_kernel<<<NB / 4, 256, 0, stream>>>(pooled, cnt, Wro1, bro1, Wro2, bro2, out);
}

// Round 4
// 635.077 us; speedup vs baseline: 2.8959x; 1.3332x over previous
//
#include <hip/hip_runtime.h>
#include <math.h>

#define NLIG 16384
#define NPROT 131072
#define NTOT (NLIG + NPROT)
#define NEDGE 2097152
#define NB 256
#define H 64
#define NBUCK 576      // NTOT = 576 * 256
#define BSHIFT 8       // bucket = dst >> 8

typedef short v4s __attribute__((ext_vector_type(4)));
typedef float v4f __attribute__((ext_vector_type(4)));

__device__ __forceinline__ unsigned short f2bf(float f) {
    unsigned int u = __float_as_uint(f);
    u += 0x7fff + ((u >> 16) & 1);   // RNE
    return (unsigned short)(u >> 16);
}
__device__ __forceinline__ float bf2f(unsigned short s) {
    return __uint_as_float(((unsigned int)s) << 16);
}

// ---------------- time embedding MLP ----------------
__global__ void time_mlp_kernel(const float* __restrict__ t,
                                const float* __restrict__ Wt1, const float* __restrict__ bt1,
                                const float* __restrict__ Wt2, const float* __restrict__ bt2,
                                float* __restrict__ t_emb) {
    int b = blockIdx.x;
    int h = threadIdx.x;
    __shared__ float emb_s[H];
    __shared__ float h1_s[H];
    float tv = t[b];
    int i = h & 31;
    float freq = expf((float)i * (-9.2103403719761836f / 31.0f));
    float e = tv * freq;
    emb_s[h] = (h < 32) ? sinf(e) : cosf(e);
    __syncthreads();
    float acc = bt1[h];
    #pragma unroll 8
    for (int k = 0; k < H; k++) acc += emb_s[k] * Wt1[k * H + h];
    float sig = 1.0f / (1.0f + expf(-acc));
    h1_s[h] = acc * sig;
    __syncthreads();
    float acc2 = bt2[h];
    #pragma unroll 8
    for (int k = 0; k < H; k++) acc2 += h1_s[k] * Wt2[k * H + h];
    t_emb[b * H + h] = acc2;
}

// ---------------- weight pre-swizzle into MFMA B-fragment order (bf16) ----------------
__global__ void wswz_kernel(const float* __restrict__ W0, const float* __restrict__ W1,
                            const float* __restrict__ W2, const float* __restrict__ W3,
                            const float* __restrict__ W4, const float* __restrict__ W5,
                            unsigned short* __restrict__ wbuf) {
    const float* Ws[6] = {W0, W1, W2, W3, W4, W5};
    int m = blockIdx.y;
    int t = blockIdx.x * 256 + threadIdx.x;   // 0..4095
    int f = t >> 8, l = (t >> 2) & 63, i = t & 3;
    int kt = f >> 2, ct = f & 3;
    int row = 16 * kt + 4 * (l >> 4) + i;
    int col = 16 * ct + (l & 15);
    wbuf[m * 4096 + t] = f2bf(Ws[m][row * H + col]);
}

// ---------------- node feature init -> bf16-packed x ----------------
__global__ void node_init_kernel(const float* __restrict__ lig_feat,
                                 const float* __restrict__ prot_feat,
                                 const int* __restrict__ lig_batch,
                                 const float* __restrict__ t_emb,
                                 const float* __restrict__ W_lig, const float* __restrict__ b_lig,
                                 const float* __restrict__ W_prot, const float* __restrict__ b_prot,
                                 unsigned int* __restrict__ xb) {
    int node = blockIdx.x * 4 + (threadIdx.x >> 6);
    int h = threadIdx.x & 63;
    if (node >= NTOT) return;
    float acc;
    if (node < NLIG) {
        int b = lig_batch[node];
        acc = b_lig[h] + t_emb[b * H + h];
        #pragma unroll
        for (int k = 0; k < 15; k++)
            acc += lig_feat[node * 15 + k] * W_lig[k * H + h];
    } else {
        int p = node - NLIG;
        acc = b_prot[h];
        #pragma unroll
        for (int k = 0; k < 8; k++)
            acc += prot_feat[p * 8 + k] * W_prot[k * H + h];
    }
    float e0 = __shfl(acc, 2 * (h & 31));
    float e1 = __shfl(acc, 2 * (h & 31) + 1);
    if (h < 32)
        xb[node * 32 + h] = (unsigned int)f2bf(e0) | ((unsigned int)f2bf(e1) << 16);
}

// ---------------- bucketed CSR build ----------------
__global__ __launch_bounds__(1024) void bucket_hist_kernel(const int* __restrict__ edge_index,
                                                           unsigned int* __restrict__ bhist) {
    __shared__ unsigned int lh[NBUCK];
    int tid = threadIdx.x;
    for (int i = tid; i < NBUCK; i += 1024) lh[i] = 0;
    __syncthreads();
    int e0 = blockIdx.x * 8192;
    #pragma unroll
    for (int k = 0; k < 8; k++) {
        int d = edge_index[NEDGE + e0 + k * 1024 + tid];
        atomicAdd(&lh[d >> BSHIFT], 1);
    }
    __syncthreads();
    for (int i = tid; i < NBUCK; i += 1024)
        if (lh[i]) atomicAdd(&bhist[i], lh[i]);
}

__global__ __launch_bounds__(1024) void bucket_scan_kernel(const unsigned int* __restrict__ bhist,
                                                           unsigned int* __restrict__ bbase,
                                                           unsigned int* __restrict__ bcursor) {
    __shared__ unsigned int s[1024];
    int tid = threadIdx.x;
    unsigned int own = (tid < NBUCK) ? bhist[tid] : 0;
    s[tid] = own;
    __syncthreads();
    for (int d = 1; d < 1024; d <<= 1) {
        unsigned int v = (tid >= d) ? s[tid - d] : 0;
        __syncthreads();
        s[tid] += v;
        __syncthreads();
    }
    unsigned int excl = s[tid] - own;
    if (tid < NBUCK) { bbase[tid] = excl; bcursor[tid] = excl; }
    if (tid == 0) bbase[NBUCK] = NEDGE;
}

__global__ __launch_bounds__(1024) void bucket_fill_kernel(const int* __restrict__ edge_index,
                                                           unsigned int* __restrict__ bcursor,
                                                           uint2* __restrict__ bucketed) {
    __shared__ uint2 stage[8192];          // 64 KB
    __shared__ unsigned int lh[NBUCK];
    __shared__ unsigned int lbeg[1024];
    __shared__ unsigned int lcur[NBUCK];
    __shared__ unsigned int gb[NBUCK];
    int tid = threadIdx.x;
    for (int i = tid; i < NBUCK; i += 1024) lh[i] = 0;
    __syncthreads();
    int e0 = blockIdx.x * 8192;
    int src[8], dst[8];
    #pragma unroll
    for (int k = 0; k < 8; k++) {
        src[k] = edge_index[e0 + k * 1024 + tid];
        dst[k] = edge_index[NEDGE + e0 + k * 1024 + tid];
        atomicAdd(&lh[dst[k] >> BSHIFT], 1);
    }
    __syncthreads();
    unsigned int own = (tid < NBUCK) ? lh[tid] : 0;
    lbeg[tid] = own;
    __syncthreads();
    for (int d = 1; d < 1024; d <<= 1) {
        unsigned int v = (tid >= d) ? lbeg[tid - d] : 0;
        __syncthreads();
        lbeg[tid] += v;
        __syncthreads();
    }
    unsigned int excl = lbeg[tid] - own;
    __syncthreads();
    lbeg[tid] = excl;
    if (tid < NBUCK) {
        lcur[tid] = excl;
        gb[tid] = atomicAdd(&bcursor[tid], lh[tid]);
    }
    __syncthreads();
    #pragma unroll
    for (int k = 0; k < 8; k++) {
        int b = dst[k] >> BSHIFT;
        unsigned int pos = atomicAdd(&lcur[b], 1);
        stage[pos] = make_uint2((unsigned int)src[k], (unsigned int)dst[k]);
    }
    __syncthreads();
    for (int i = tid; i < 8192; i += 1024) {
        uint2 v = stage[i];
        int b = v.y >> BSHIFT;
        bucketed[gb[b] + (i - lbeg[b])] = v;
    }
}

__global__ __launch_bounds__(512) void bucket_csr_kernel(const uint2* __restrict__ bucketed,
                                                         const unsigned int* __restrict__ bbase,
                                                         int* __restrict__ off,
                                                         int* __restrict__ csr_src) {
    __shared__ uint2 stage[4608];          // 36 KB
    __shared__ unsigned int csr_l[4608];   // 18 KB
    __shared__ unsigned int lh[256];
    __shared__ unsigned int lbeg[512];
    __shared__ unsigned int lcur[256];
    int b = blockIdx.x, tid = threadIdx.x;
    unsigned int base = bbase[b];
    int cnt = (int)(bbase[b + 1] - base);
    if (cnt > 4608) cnt = 4608;   // 16-sigma guard, never triggers
    for (int i = tid; i < 256; i += 512) lh[i] = 0;
    __syncthreads();
    for (int i = tid; i < cnt; i += 512) {
        uint2 v = bucketed[base + i];
        stage[i] = v;
        atomicAdd(&lh[v.y & 255], 1);
    }
    __syncthreads();
    unsigned int own = (tid < 256) ? lh[tid] : 0;
    lbeg[tid] = own;
    __syncthreads();
    for (int d = 1; d < 512; d <<= 1) {
        unsigned int v = (tid >= d) ? lbeg[tid - d] : 0;
        __syncthreads();
        lbeg[tid] += v;
        __syncthreads();
    }
    unsigned int excl = lbeg[tid] - own;
    __syncthreads();
    lbeg[tid] = excl;
    if (tid < 256) {
        lcur[tid] = excl;
        off[b * 256 + tid] = (int)(base + excl);
    }
    if (b == 0 && tid == 0) off[NTOT] = NEDGE;
    __syncthreads();
    for (int i = tid; i < cnt; i += 512) {
        uint2 v = stage[i];
        unsigned int p = atomicAdd(&lcur[v.y & 255], 1);
        csr_l[p] = v.x;
    }
    __syncthreads();
    for (int i = tid; i < cnt; i += 512)
        csr_src[base + i] = (int)csr_l[i];
}

// ---------------- fused conv: gather (bf16) + MFMA combine ----------------
__global__ __launch_bounds__(256) void conv_kernel(const int* __restrict__ off,
                                                   const int* __restrict__ csr,
                                                   const unsigned int* __restrict__ xb,
                                                   const unsigned short* __restrict__ wbuf,
                                                   const float* __restrict__ brel,
                                                   unsigned int* __restrict__ xob) {
    __shared__ unsigned int wlds[4096];
    __shared__ unsigned short agg_s[64 * 72];
    __shared__ unsigned short xs_s[64 * 72];
    const int tid = threadIdx.x;
    const int w = tid >> 6, l = tid & 63;
    const int node0 = blockIdx.x * 64;
    const unsigned int* wsrc = (const unsigned int*)wbuf;
    for (int i = tid; i < 4096; i += 256) wlds[i] = wsrc[i];
    __syncthreads();

    const int half = l >> 5, c = l & 31;
    for (int i = 0; i < 16; i++) {
        int ln = w * 16 + i;
        int node = node0 + ln;
        int beg = off[node], end = off[node + 1];
        float a0 = 0.f, a1 = 0.f;
        for (int j0 = beg; j0 < end; j0 += 64) {
            int cnt = end - j0; if (cnt > 64) cnt = 64;
            int id = (j0 + l < end) ? csr[j0 + l] : 0;
            int j = 0;
            for (; j + 1 < cnt; j += 2) {
                int nb = __shfl(id, j + half);
                unsigned int u = xb[nb * 32 + c];
                a0 += bf2f((unsigned short)(u & 0xffffu));
                a1 += bf2f((unsigned short)(u >> 16));
            }
            if (j < cnt) {
                int nb = __shfl(id, j);
                if (half == 0) {
                    unsigned int u = xb[nb * 32 + c];
                    a0 += bf2f((unsigned short)(u & 0xffffu));
                    a1 += bf2f((unsigned short)(u >> 16));
                }
            }
        }
        a0 += __shfl_xor(a0, 32);
        a1 += __shfl_xor(a1, 32);
        if (half == 0)
            *(unsigned int*)&agg_s[ln * 72 + 2 * c] =
                (unsigned int)f2bf(a0) | ((unsigned int)f2bf(a1) << 16);
    }
    #pragma unroll
    for (int i2 = 0; i2 < 8; i2++) {
        int r = w * 16 + i2 * 2 + half;
        *(unsigned int*)&xs_s[r * 72 + 2 * c] = xb[(node0 + r) * 32 + c];
    }
    v4f acc[4];
    #pragma unroll
    for (int ct = 0; ct < 4; ct++) acc[ct] = (v4f){0.f, 0.f, 0.f, 0.f};
    const int arow = w * 16 + (l & 15);
    const int g4 = 4 * (l >> 4);
    #pragma unroll
    for (int kt = 0; kt < 4; kt++) {
        v4s a_agg = *(const v4s*)&agg_s[arow * 72 + kt * 16 + g4];
        v4s a_x   = *(const v4s*)&xs_s [arow * 72 + kt * 16 + g4];
        #pragma unroll
        for (int ct = 0; ct < 4; ct++) {
            int f = kt * 4 + ct;
            v4s wr = *(const v4s*)&wlds[f * 128 + l * 2];
            v4s wo = *(const v4s*)&wlds[2048 + f * 128 + l * 2];
            acc[ct] = __builtin_amdgcn_mfma_f32_16x16x16bf16_1k(a_agg, wr, acc[ct], 0, 0, 0);
            acc[ct] = __builtin_amdgcn_mfma_f32_16x16x16bf16_1k(a_x,   wo, acc[ct], 0, 0, 0);
        }
    }
    #pragma unroll
    for (int ct = 0; ct < 4; ct++) {
        float bv = brel[ct * 16 + (l & 15)];
        #pragma unroll
        for (int r = 0; r < 4; r++)
            xs_s[(w * 16 + g4 + r) * 72 + ct * 16 + (l & 15)] = f2bf(acc[ct][r] + bv);
    }
    __syncthreads();
    {
        int row = tid >> 2, q = tid & 3;
        const unsigned int* srcp = (const unsigned int*)&xs_s[row * 72 + q * 16];
        uint4 v0 = *(const uint4*)(srcp);
        uint4 v1 = *(const uint4*)(srcp + 4);
        *(uint4*)&xob[(node0 + row) * 32 + q * 8] = v0;
        *(uint4*)&xob[(node0 + row) * 32 + q * 8 + 4] = v1;
    }
}

// ---------------- ligand pooling (bf16 x) ----------------
__global__ void pool_kernel(const unsigned int* __restrict__ xb,
                            const int* __restrict__ lig_batch,
                            float* __restrict__ pooled, float* __restrict__ cnt) {
    int node = blockIdx.x * 4 + (threadIdx.x >> 6);
    int h = threadIdx.x & 63;
    if (node >= NLIG) return;
    int b = lig_batch[node];
    unsigned int u = xb[node * 32 + (h >> 1)];
    float v = bf2f((unsigned short)((h & 1) ? (u >> 16) : (u & 0xffffu)));
    unsafeAtomicAdd(&pooled[b * H + h], v);
    if (h == 0) unsafeAtomicAdd(&cnt[b], 1.0f);
}

// ---------------- readout ----------------
__global__ void readout_kernel(const float* __restrict__ pooled, const float* __restrict__ cnt,
                               const float* __restrict__ Wro1, const float* __restrict__ bro1,
                               const float* __restrict__ Wro2, const float* __restrict__ bro2,
                               float* __restrict__ out) {
    __shared__ float pm[4][H];
    int w = threadIdx.x >> 6;
    int h = threadIdx.x & 63;
    int b = blockIdx.x * 4 + w;
    float c = fmaxf(cnt[b], 1.0f);
    pm[w][h] = pooled[b * H + h] / c;
    __syncthreads();
    float acc = bro1[h];
    #pragma unroll 8
    for (int k = 0; k < H; k++) acc += pm[w][k] * Wro1[k * H + h];
    float sig = 1.0f / (1.0f + expf(-acc));
    float s = acc * sig;
    float r = s * Wro2[h];
    #pragma unroll
    for (int off = 32; off; off >>= 1) r += __shfl_down(r, off);
    if (h == 0) out[b] = r + bro2[0];
}

extern "C" void kernel_launch(void* const* d_in, const int* in_sizes, int n_in,
                              void* d_out, int out_size, void* d_ws, size_t ws_size,
                              hipStream_t stream) {
    const float* lig_feat  = (const float*)d_in[1];
    const float* prot_feat = (const float*)d_in[3];
    const float* t         = (const float*)d_in[4];
    const int*   lig_batch = (const int*)d_in[5];
    const int*   edge_index= (const int*)d_in[7];
    const float* W_lig  = (const float*)d_in[8];
    const float* b_lig  = (const float*)d_in[9];
    const float* W_prot = (const float*)d_in[10];
    const float* b_prot = (const float*)d_in[11];
    const float* Wt1 = (const float*)d_in[12];
    const float* bt1 = (const float*)d_in[13];
    const float* Wt2 = (const float*)d_in[14];
    const float* bt2 = (const float*)d_in[15];
    const float* Wrel[3]  = {(const float*)d_in[16], (const float*)d_in[19], (const float*)d_in[22]};
    const float* brel[3]  = {(const float*)d_in[17], (const float*)d_in[20], (const float*)d_in[23]};
    const float* Wroot[3] = {(const float*)d_in[18], (const float*)d_in[21], (const float*)d_in[24]};
    const float* Wro1 = (const float*)d_in[25];
    const float* bro1 = (const float*)d_in[26];
    const float* Wro2 = (const float*)d_in[27];
    const float* bro2 = (const float*)d_in[28];
    float* out = (float*)d_out;

    char* ws = (char*)d_ws;
    int*            off_a   = (int*)(ws);                       // (NTOT+1) ints
    unsigned int*   bhist   = (unsigned int*)(ws + 655360);
    unsigned int*   bbase   = (unsigned int*)(ws + 659456);
    unsigned int*   bcursor = (unsigned int*)(ws + 665600);
    float*          t_emb   = (float*)(ws + 1376256);
    float*          pooled  = (float*)(ws + 1441792);
    float*          cnt     = (float*)(ws + 1507328);
    unsigned short* wbuf    = (unsigned short*)(ws + 1572864);  // 48 KB
    int*            csr_src = (int*)(ws + 2097152);             // 8 MB
    uint2*          bucketed= (uint2*)(ws + 10485760);          // 16 MB
    unsigned int*   xb0     = (unsigned int*)(ws + 27262976);   // 18 MB
    unsigned int*   xb1     = (unsigned int*)(ws + 46137344);   // 18 MB
    unsigned int*   xbs[2]  = {xb0, xb1};

    time_mlp_kernel<<<NB, H, 0, stream>>>(t, Wt1, bt1, Wt2, bt2, t_emb);
    wswz_kernel<<<dim3(16, 6), 256, 0, stream>>>(Wrel[0], Wroot[0], Wrel[1], Wroot[1],
                                                 Wrel[2], Wroot[2], wbuf);
    node_init_kernel<<<NTOT / 4, 256, 0, stream>>>(lig_feat, prot_feat, lig_batch, t_emb,
                                                   W_lig, b_lig, W_prot, b_prot, xb0);

    // ---- bucketed CSR build ----
    hipMemsetAsync(bhist, 0, NBUCK * sizeof(unsigned int), stream);
    bucket_hist_kernel<<<NEDGE / 8192, 1024, 0, stream>>>(edge_index, bhist);
    bucket_scan_kernel<<<1, 1024, 0, stream>>>(bhist, bbase, bcursor);
    bucket_fill_kernel<<<NEDGE / 8192, 1024, 0, stream>>>(edge_index, bcursor, bucketed);
    bucket_csr_kernel<<<NBUCK, 512, 0, stream>>>(bucketed, bbase, off_a, csr_src);

    // ---- 3 fused graph convs ----
    for (int lyr = 0; lyr < 3; lyr++) {
        unsigned int* cur = xbs[lyr & 1];
        unsigned int* nxt = xbs[(lyr + 1) & 1];
        conv_kernel<<<NTOT / 64, 256, 0, stream>>>(off_a, csr_src, cur,
                                                   wbuf + lyr * 8192, brel[lyr], nxt);
    }
    unsigned int* xfin = xbs[1];

    hipMemsetAsync(pooled, 0, (size_t)(NB * H + NB) * sizeof(float), stream);
    pool_kernel<<<NLIG / 4, 256, 0, stream>>>(xfin, lig_batch, pooled, cnt);
    readout_kernel<<<NB / 4, 256, 0, stream>>>(pooled, cnt, Wro1, bro1, Wro2, bro2, out);
}

// Round 5
// 347.179 us; speedup vs baseline: 5.2973x; 1.8293x over previous
//
#include <hip/hip_runtime.h>
#include <math.h>

#define NLIG 16384
#define NPROT 131072
#define NTOT (NLIG + NPROT)
#define NEDGE 2097152
#define NB 256
#define H 64
#define NBUCK 576      // NTOT = 576 * 256
#define BSHIFT 8       // bucket = dst >> 8

typedef short v4s __attribute__((ext_vector_type(4)));
typedef float v4f __attribute__((ext_vector_type(4)));

__device__ __forceinline__ unsigned short f2bf(float f) {
    unsigned int u = __float_as_uint(f);
    u += 0x7fff + ((u >> 16) & 1);   // RNE
    return (unsigned short)(u >> 16);
}
__device__ __forceinline__ float bf2f(unsigned short s) {
    return __uint_as_float(((unsigned int)s) << 16);
}
__device__ __forceinline__ float bflo(unsigned int u) {
    return __uint_as_float(u << 16);
}
__device__ __forceinline__ float bfhi(unsigned int u) {
    return __uint_as_float(u & 0xffff0000u);
}

// ---------------- time embedding MLP ----------------
__global__ void time_mlp_kernel(const float* __restrict__ t,
                                const float* __restrict__ Wt1, const float* __restrict__ bt1,
                                const float* __restrict__ Wt2, const float* __restrict__ bt2,
                                float* __restrict__ t_emb) {
    int b = blockIdx.x;
    int h = threadIdx.x;
    __shared__ float emb_s[H];
    __shared__ float h1_s[H];
    float tv = t[b];
    int i = h & 31;
    float freq = expf((float)i * (-9.2103403719761836f / 31.0f));
    float e = tv * freq;
    emb_s[h] = (h < 32) ? sinf(e) : cosf(e);
    __syncthreads();
    float acc = bt1[h];
    #pragma unroll 8
    for (int k = 0; k < H; k++) acc += emb_s[k] * Wt1[k * H + h];
    float sig = 1.0f / (1.0f + expf(-acc));
    h1_s[h] = acc * sig;
    __syncthreads();
    float acc2 = bt2[h];
    #pragma unroll 8
    for (int k = 0; k < H; k++) acc2 += h1_s[k] * Wt2[k * H + h];
    t_emb[b * H + h] = acc2;
}

// ---------------- weight pre-swizzle into MFMA B-fragment order (bf16) ----------------
__global__ void wswz_kernel(const float* __restrict__ W0, const float* __restrict__ W1,
                            const float* __restrict__ W2, const float* __restrict__ W3,
                            const float* __restrict__ W4, const float* __restrict__ W5,
                            unsigned short* __restrict__ wbuf) {
    const float* Ws[6] = {W0, W1, W2, W3, W4, W5};
    int m = blockIdx.y;
    int t = blockIdx.x * 256 + threadIdx.x;   // 0..4095
    int f = t >> 8, l = (t >> 2) & 63, i = t & 3;
    int kt = f >> 2, ct = f & 3;
    int row = 16 * kt + 4 * (l >> 4) + i;
    int col = 16 * ct + (l & 15);
    wbuf[m * 4096 + t] = f2bf(Ws[m][row * H + col]);
}

// ---------------- node feature init -> bf16-packed x ----------------
__global__ void node_init_kernel(const float* __restrict__ lig_feat,
                                 const float* __restrict__ prot_feat,
                                 const int* __restrict__ lig_batch,
                                 const float* __restrict__ t_emb,
                                 const float* __restrict__ W_lig, const float* __restrict__ b_lig,
                                 const float* __restrict__ W_prot, const float* __restrict__ b_prot,
                                 unsigned int* __restrict__ xb) {
    int node = blockIdx.x * 4 + (threadIdx.x >> 6);
    int h = threadIdx.x & 63;
    if (node >= NTOT) return;
    float acc;
    if (node < NLIG) {
        int b = lig_batch[node];
        acc = b_lig[h] + t_emb[b * H + h];
        #pragma unroll
        for (int k = 0; k < 15; k++)
            acc += lig_feat[node * 15 + k] * W_lig[k * H + h];
    } else {
        int p = node - NLIG;
        acc = b_prot[h];
        #pragma unroll
        for (int k = 0; k < 8; k++)
            acc += prot_feat[p * 8 + k] * W_prot[k * H + h];
    }
    float e0 = __shfl(acc, 2 * (h & 31));
    float e1 = __shfl(acc, 2 * (h & 31) + 1);
    if (h < 32)
        xb[node * 32 + h] = (unsigned int)f2bf(e0) | ((unsigned int)f2bf(e1) << 16);
}

// ---------------- bucketed CSR build ----------------
__global__ __launch_bounds__(1024) void bucket_hist_kernel(const int* __restrict__ edge_index,
                                                           unsigned int* __restrict__ bhist) {
    __shared__ unsigned int lh[NBUCK];
    int tid = threadIdx.x;
    for (int i = tid; i < NBUCK; i += 1024) lh[i] = 0;
    __syncthreads();
    int e0 = blockIdx.x * 8192;
    #pragma unroll
    for (int k = 0; k < 8; k++) {
        int d = edge_index[NEDGE + e0 + k * 1024 + tid];
        atomicAdd(&lh[d >> BSHIFT], 1);
    }
    __syncthreads();
    for (int i = tid; i < NBUCK; i += 1024)
        if (lh[i]) atomicAdd(&bhist[i], lh[i]);
}

__global__ __launch_bounds__(1024) void bucket_scan_kernel(const unsigned int* __restrict__ bhist,
                                                           unsigned int* __restrict__ bbase,
                                                           unsigned int* __restrict__ bcursor) {
    __shared__ unsigned int s[1024];
    int tid = threadIdx.x;
    unsigned int own = (tid < NBUCK) ? bhist[tid] : 0;
    s[tid] = own;
    __syncthreads();
    for (int d = 1; d < 1024; d <<= 1) {
        unsigned int v = (tid >= d) ? s[tid - d] : 0;
        __syncthreads();
        s[tid] += v;
        __syncthreads();
    }
    unsigned int excl = s[tid] - own;
    if (tid < NBUCK) { bbase[tid] = excl; bcursor[tid] = excl; }
    if (tid == 0) bbase[NBUCK] = NEDGE;
}

__global__ __launch_bounds__(1024) void bucket_fill_kernel(const int* __restrict__ edge_index,
                                                           unsigned int* __restrict__ bcursor,
                                                           uint2* __restrict__ bucketed) {
    __shared__ uint2 stage[8192];          // 64 KB
    __shared__ unsigned int lh[NBUCK];
    __shared__ unsigned int lbeg[1024];
    __shared__ unsigned int lcur[NBUCK];
    __shared__ unsigned int gb[NBUCK];
    int tid = threadIdx.x;
    for (int i = tid; i < NBUCK; i += 1024) lh[i] = 0;
    __syncthreads();
    int e0 = blockIdx.x * 8192;
    int src[8], dst[8];
    #pragma unroll
    for (int k = 0; k < 8; k++) {
        src[k] = edge_index[e0 + k * 1024 + tid];
        dst[k] = edge_index[NEDGE + e0 + k * 1024 + tid];
        atomicAdd(&lh[dst[k] >> BSHIFT], 1);
    }
    __syncthreads();
    unsigned int own = (tid < NBUCK) ? lh[tid] : 0;
    lbeg[tid] = own;
    __syncthreads();
    for (int d = 1; d < 1024; d <<= 1) {
        unsigned int v = (tid >= d) ? lbeg[tid - d] : 0;
        __syncthreads();
        lbeg[tid] += v;
        __syncthreads();
    }
    unsigned int excl = lbeg[tid] - own;
    __syncthreads();
    lbeg[tid] = excl;
    if (tid < NBUCK) {
        lcur[tid] = excl;
        gb[tid] = atomicAdd(&bcursor[tid], lh[tid]);
    }
    __syncthreads();
    #pragma unroll
    for (int k = 0; k < 8; k++) {
        int b = dst[k] >> BSHIFT;
        unsigned int pos = atomicAdd(&lcur[b], 1);
        stage[pos] = make_uint2((unsigned int)src[k], (unsigned int)dst[k]);
    }
    __syncthreads();
    for (int i = tid; i < 8192; i += 1024) {
        uint2 v = stage[i];
        int b = v.y >> BSHIFT;
        bucketed[gb[b] + (i - lbeg[b])] = v;
    }
}

__global__ __launch_bounds__(512) void bucket_csr_kernel(const uint2* __restrict__ bucketed,
                                                         const unsigned int* __restrict__ bbase,
                                                         int* __restrict__ off,
                                                         int* __restrict__ csr_src) {
    __shared__ uint2 stage[4608];          // 36 KB
    __shared__ unsigned int csr_l[4608];   // 18 KB
    __shared__ unsigned int lh[256];
    __shared__ unsigned int lbeg[512];
    __shared__ unsigned int lcur[256];
    int b = blockIdx.x, tid = threadIdx.x;
    unsigned int base = bbase[b];
    int cnt = (int)(bbase[b + 1] - base);
    if (cnt > 4608) cnt = 4608;   // 16-sigma guard, never triggers
    for (int i = tid; i < 256; i += 512) lh[i] = 0;
    __syncthreads();
    for (int i = tid; i < cnt; i += 512) {
        uint2 v = bucketed[base + i];
        stage[i] = v;
        atomicAdd(&lh[v.y & 255], 1);
    }
    __syncthreads();
    unsigned int own = (tid < 256) ? lh[tid] : 0;
    lbeg[tid] = own;
    __syncthreads();
    for (int d = 1; d < 512; d <<= 1) {
        unsigned int v = (tid >= d) ? lbeg[tid - d] : 0;
        __syncthreads();
        lbeg[tid] += v;
        __syncthreads();
    }
    unsigned int excl = lbeg[tid] - own;
    __syncthreads();
    lbeg[tid] = excl;
    if (tid < 256) {
        lcur[tid] = excl;
        off[b * 256 + tid] = (int)(base + excl);
    }
    if (b == 0 && tid == 0) off[NTOT] = NEDGE;
    __syncthreads();
    for (int i = tid; i < cnt; i += 512) {
        uint2 v = stage[i];
        unsigned int p = atomicAdd(&lcur[v.y & 255], 1);
        csr_l[p] = v.x;
    }
    __syncthreads();
    for (int i = tid; i < cnt; i += 512)
        csr_src[base + i] = (int)csr_l[i];
}

// ---------------- fused conv: wide gather (uint4, 8 nbrs/round) + MFMA combine ----------------
// 512 threads = 8 waves, 128-node tile. Wave w owns rows [16w,16w+16).
// Gather: slot s=l>>3 handles neighbor j+s, quad q=l&7 handles features 8q..8q+7.
// Reduce across slots via shfl_xor(8,16,32). agg -> LDS (wave-local rows).
// MFMA: A_agg from LDS, A_x direct from global, B frags (weights) from LDS.
// Epilogue reuses agg tile (wave-local rows) -> barrier -> coalesced writeout.
__global__ __launch_bounds__(512, 6) void conv_kernel(const int* __restrict__ off,
                                                      const int* __restrict__ csr,
                                                      const unsigned int* __restrict__ xb,
                                                      const unsigned short* __restrict__ wbuf,
                                                      const float* __restrict__ brel,
                                                      unsigned int* __restrict__ xob) {
    __shared__ unsigned int wlds[4096];            // 16 KB: rel frags [0,2048), root [2048,4096)
    __shared__ unsigned short agg_s[128 * 72];     // 18 KB, padded rows
    const int tid = threadIdx.x;
    const int w = tid >> 6, l = tid & 63;
    const int node0 = blockIdx.x * 128;
    const unsigned int* wsrc = (const unsigned int*)wbuf;
    #pragma unroll
    for (int i = 0; i < 8; i++) wlds[i * 512 + tid] = wsrc[i * 512 + tid];
    __syncthreads();

    const int s = l >> 3, q = l & 7;
    // all 17 offsets for this wave's 16 nodes in one vector load
    int offv = (l <= 16) ? off[node0 + w * 16 + l] : 0;

    for (int i = 0; i < 16; i++) {
        int ln = w * 16 + i;
        int beg = __shfl(offv, i);
        int end = __shfl(offv, i + 1);
        float a0 = 0.f, a1 = 0.f, a2 = 0.f, a3 = 0.f;
        float a4 = 0.f, a5 = 0.f, a6 = 0.f, a7 = 0.f;
        for (int j0 = beg; j0 < end; j0 += 64) {
            int cnt = end - j0; if (cnt > 64) cnt = 64;
            int id = (j0 + l < end) ? csr[j0 + l] : 0;
            for (int j = 0; j < cnt; j += 8) {
                int nb = __shfl(id, j + s);
                uint4 u = *(const uint4*)&xb[nb * 32 + q * 4];
                if (j + s >= cnt) { u.x = 0; u.y = 0; u.z = 0; u.w = 0; }
                a0 += bflo(u.x); a1 += bfhi(u.x);
                a2 += bflo(u.y); a3 += bfhi(u.y);
                a4 += bflo(u.z); a5 += bfhi(u.z);
                a6 += bflo(u.w); a7 += bfhi(u.w);
            }
        }
        // reduce across the 8 neighbor slots
        #pragma unroll
        for (int m = 8; m <= 32; m <<= 1) {
            a0 += __shfl_xor(a0, m); a1 += __shfl_xor(a1, m);
            a2 += __shfl_xor(a2, m); a3 += __shfl_xor(a3, m);
            a4 += __shfl_xor(a4, m); a5 += __shfl_xor(a5, m);
            a6 += __shfl_xor(a6, m); a7 += __shfl_xor(a7, m);
        }
        // a1 is the high half of the same dword as a0, etc.
        unsigned int p0 = (unsigned int)f2bf(a0) | ((unsigned int)f2bf(a1) << 16);
        unsigned int p1 = (unsigned int)f2bf(a2) | ((unsigned int)f2bf(a3) << 16);
        unsigned int p2 = (unsigned int)f2bf(a4) | ((unsigned int)f2bf(a5) << 16);
        unsigned int p3 = (unsigned int)f2bf(a6) | ((unsigned int)f2bf(a7) << 16);
        if (s == 0)
            *(uint4*)&agg_s[ln * 72 + q * 8] = make_uint4(p0, p1, p2, p3);
    }

    // ---- MFMA phase (wave-local rows only; no barrier needed) ----
    const int arow = w * 16 + (l & 15);
    const int g = l >> 4;          // 0..3
    const int g4 = 4 * g;
    v4s ax[4];
    #pragma unroll
    for (int kt = 0; kt < 4; kt++)
        ax[kt] = *(const v4s*)&xb[(node0 + arow) * 32 + kt * 8 + 2 * g];
    v4f acc[4];
    #pragma unroll
    for (int ct = 0; ct < 4; ct++) acc[ct] = (v4f){0.f, 0.f, 0.f, 0.f};
    #pragma unroll
    for (int kt = 0; kt < 4; kt++) {
        v4s a_agg = *(const v4s*)&agg_s[arow * 72 + kt * 16 + g4];
        #pragma unroll
        for (int ct = 0; ct < 4; ct++) {
            int f = kt * 4 + ct;
            v4s wr = *(const v4s*)&wlds[f * 128 + l * 2];
            v4s wo = *(const v4s*)&wlds[2048 + f * 128 + l * 2];
            acc[ct] = __builtin_amdgcn_mfma_f32_16x16x16bf16_1k(a_agg, wr, acc[ct], 0, 0, 0);
            acc[ct] = __builtin_amdgcn_mfma_f32_16x16x16bf16_1k(ax[kt], wo, acc[ct], 0, 0, 0);
        }
    }
    // ---- epilogue into agg tile (own rows; frag reads already done) ----
    #pragma unroll
    for (int ct = 0; ct < 4; ct++) {
        float bv = brel[ct * 16 + (l & 15)];
        #pragma unroll
        for (int r = 0; r < 4; r++)
            agg_s[(w * 16 + g4 + r) * 72 + ct * 16 + (l & 15)] = f2bf(acc[ct][r] + bv);
    }
    __syncthreads();
    // coalesced writeout: 128 rows x 32 dwords
    {
        int row = tid >> 2, qq = tid & 3;
        const unsigned int* srcp = (const unsigned int*)&agg_s[row * 72 + qq * 16];
        uint4 v0 = *(const uint4*)(srcp);
        uint4 v1 = *(const uint4*)(srcp + 4);
        *(uint4*)&xob[(node0 + row) * 32 + qq * 8] = v0;
        *(uint4*)&xob[(node0 + row) * 32 + qq * 8 + 4] = v1;
    }
}

// ---------------- ligand pooling (bf16 x) ----------------
__global__ void pool_kernel(const unsigned int* __restrict__ xb,
                            const int* __restrict__ lig_batch,
                            float* __restrict__ pooled, float* __restrict__ cnt) {
    int node = blockIdx.x * 4 + (threadIdx.x >> 6);
    int h = threadIdx.x & 63;
    if (node >= NLIG) return;
    int b = lig_batch[node];
    unsigned int u = xb[node * 32 + (h >> 1)];
    float v = bf2f((unsigned short)((h & 1) ? (u >> 16) : (u & 0xffffu)));
    unsafeAtomicAdd(&pooled[b * H + h], v);
    if (h == 0) unsafeAtomicAdd(&cnt[b], 1.0f);
}

// ---------------- readout ----------------
__global__ void readout_kernel(const float* __restrict__ pooled, const float* __restrict__ cnt,
                               const float* __restrict__ Wro1, const float* __restrict__ bro1,
                               const float* __restrict__ Wro2, const float* __restrict__ bro2,
                               float* __restrict__ out) {
    __shared__ float pm[4][H];
    int w = threadIdx.x >> 6;
    int h = threadIdx.x & 63;
    int b = blockIdx.x * 4 + w;
    float c = fmaxf(cnt[b], 1.0f);
    pm[w][h] = pooled[b * H + h] / c;
    __syncthreads();
    float acc = bro1[h];
    #pragma unroll 8
    for (int k = 0; k < H; k++) acc += pm[w][k] * Wro1[k * H + h];
    float sig = 1.0f / (1.0f + expf(-acc));
    float s = acc * sig;
    float r = s * Wro2[h];
    #pragma unroll
    for (int off = 32; off; off >>= 1) r += __shfl_down(r, off);
    if (h == 0) out[b] = r + bro2[0];
}

extern "C" void kernel_launch(void* const* d_in, const int* in_sizes, int n_in,
                              void* d_out, int out_size, void* d_ws, size_t ws_size,
                              hipStream_t stream) {
    const float* lig_feat  = (const float*)d_in[1];
    const float* prot_feat = (const float*)d_in[3];
    const float* t         = (const float*)d_in[4];
    const int*   lig_batch = (const int*)d_in[5];
    const int*   edge_index= (const int*)d_in[7];
    const float* W_lig  = (const float*)d_in[8];
    const float* b_lig  = (const float*)d_in[9];
    const float* W_prot = (const float*)d_in[10];
    const float* b_prot = (const float*)d_in[11];
    const float* Wt1 = (const float*)d_in[12];
    const float* bt1 = (const float*)d_in[13];
    const float* Wt2 = (const float*)d_in[14];
    const float* bt2 = (const float*)d_in[15];
    const float* Wrel[3]  = {(const float*)d_in[16], (const float*)d_in[19], (const float*)d_in[22]};
    const float* brel[3]  = {(const float*)d_in[17], (const float*)d_in[20], (const float*)d_in[23]};
    const float* Wroot[3] = {(const float*)d_in[18], (const float*)d_in[21], (const float*)d_in[24]};
    const float* Wro1 = (const float*)d_in[25];
    const float* bro1 = (const float*)d_in[26];
    const float* Wro2 = (const float*)d_in[27];
    const float* bro2 = (const float*)d_in[28];
    float* out = (float*)d_out;

    char* ws = (char*)d_ws;
    int*            off_a   = (int*)(ws);                       // (NTOT+1) ints
    unsigned int*   bhist   = (unsigned int*)(ws + 655360);
    unsigned int*   bbase   = (unsigned int*)(ws + 659456);
    unsigned int*   bcursor = (unsigned int*)(ws + 665600);
    float*          t_emb   = (float*)(ws + 1376256);
    float*          pooled  = (float*)(ws + 1441792);
    float*          cnt     = (float*)(ws + 1507328);
    unsigned short* wbuf    = (unsigned short*)(ws + 1572864);  // 48 KB
    int*            csr_src = (int*)(ws + 2097152);             // 8 MB
    uint2*          bucketed= (uint2*)(ws + 10485760);          // 16 MB
    unsigned int*   xb0     = (unsigned int*)(ws + 27262976);   // 18 MB
    unsigned int*   xb1     = (unsigned int*)(ws + 46137344);   // 18 MB
    unsigned int*   xbs[2]  = {xb0, xb1};

    time_mlp_kernel<<<NB, H, 0, stream>>>(t, Wt1, bt1, Wt2, bt2, t_emb);
    wswz_kernel<<<dim3(16, 6), 256, 0, stream>>>(Wrel[0], Wroot[0], Wrel[1], Wroot[1],
                                                 Wrel[2], Wroot[2], wbuf);
    node_init_kernel<<<NTOT / 4, 256, 0, stream>>>(lig_feat, prot_feat, lig_batch, t_emb,
                                                   W_lig, b_lig, W_prot, b_prot, xb0);

    // ---- bucketed CSR build ----
    hipMemsetAsync(bhist, 0, NBUCK * sizeof(unsigned int), stream);
    bucket_hist_kernel<<<NEDGE / 8192, 1024, 0, stream>>>(edge_index, bhist);
    bucket_scan_kernel<<<1, 1024, 0, stream>>>(bhist, bbase, bcursor);
    bucket_fill_kernel<<<NEDGE / 8192, 1024, 0, stream>>>(edge_index, bcursor, bucketed);
    bucket_csr_kernel<<<NBUCK, 512, 0, stream>>>(bucketed, bbase, off_a, csr_src);

    // ---- 3 fused graph convs ----
    for (int lyr = 0; lyr < 3; lyr++) {
        unsigned int* cur = xbs[lyr & 1];
        unsigned int* nxt = xbs[(lyr + 1) & 1];
        conv_kernel<<<NTOT / 128, 512, 0, stream>>>(off_a, csr_src, cur,
                                                    wbuf + lyr * 8192, brel[lyr], nxt);
    }
    unsigned int* xfin = xbs[1];

    hipMemsetAsync(pooled, 0, (size_t)(NB * H + NB) * sizeof(float), stream);
    pool_kernel<<<NLIG / 4, 256, 0, stream>>>(xfin, lig_batch, pooled, cnt);
    readout_kernel<<<NB / 4, 256, 0, stream>>>(pooled, cnt, Wro1, bro1, Wro2, bro2, out);
}

// Round 6
// 324.309 us; speedup vs baseline: 5.6709x; 1.0705x over previous
//
#include <hip/hip_runtime.h>
#include <math.h>

#define NLIG 16384
#define NPROT 131072
#define NTOT (NLIG + NPROT)
#define NEDGE 2097152
#define NB 256
#define H 64
#define NBUCK 576      // NTOT = 576 * 256
#define BSHIFT 8       // bucket = dst >> 8

typedef short v4s __attribute__((ext_vector_type(4)));
typedef float v4f __attribute__((ext_vector_type(4)));

__device__ __forceinline__ unsigned short f2bf(float f) {
    unsigned int u = __float_as_uint(f);
    u += 0x7fff + ((u >> 16) & 1);   // RNE
    return (unsigned short)(u >> 16);
}
__device__ __forceinline__ float bf2f(unsigned short s) {
    return __uint_as_float(((unsigned int)s) << 16);
}
__device__ __forceinline__ float bflo(unsigned int u) {
    return __uint_as_float(u << 16);
}
__device__ __forceinline__ float bfhi(unsigned int u) {
    return __uint_as_float(u & 0xffff0000u);
}

// ---------------- time embedding MLP ----------------
__global__ void time_mlp_kernel(const float* __restrict__ t,
                                const float* __restrict__ Wt1, const float* __restrict__ bt1,
                                const float* __restrict__ Wt2, const float* __restrict__ bt2,
                                float* __restrict__ t_emb) {
    int b = blockIdx.x;
    int h = threadIdx.x;
    __shared__ float emb_s[H];
    __shared__ float h1_s[H];
    float tv = t[b];
    int i = h & 31;
    float freq = expf((float)i * (-9.2103403719761836f / 31.0f));
    float e = tv * freq;
    emb_s[h] = (h < 32) ? sinf(e) : cosf(e);
    __syncthreads();
    float acc = bt1[h];
    #pragma unroll 8
    for (int k = 0; k < H; k++) acc += emb_s[k] * Wt1[k * H + h];
    float sig = 1.0f / (1.0f + expf(-acc));
    h1_s[h] = acc * sig;
    __syncthreads();
    float acc2 = bt2[h];
    #pragma unroll 8
    for (int k = 0; k < H; k++) acc2 += h1_s[k] * Wt2[k * H + h];
    t_emb[b * H + h] = acc2;
}

// ---------------- weight pre-swizzle into MFMA B-fragment order (bf16) ----------------
__global__ void wswz_kernel(const float* __restrict__ W0, const float* __restrict__ W1,
                            const float* __restrict__ W2, const float* __restrict__ W3,
                            const float* __restrict__ W4, const float* __restrict__ W5,
                            unsigned short* __restrict__ wbuf) {
    const float* Ws[6] = {W0, W1, W2, W3, W4, W5};
    int m = blockIdx.y;
    int t = blockIdx.x * 256 + threadIdx.x;   // 0..4095
    int f = t >> 8, l = (t >> 2) & 63, i = t & 3;
    int kt = f >> 2, ct = f & 3;
    int row = 16 * kt + 4 * (l >> 4) + i;
    int col = 16 * ct + (l & 15);
    wbuf[m * 4096 + t] = f2bf(Ws[m][row * H + col]);
}

// ---------------- node feature init -> bf16-packed x ----------------
__global__ void node_init_kernel(const float* __restrict__ lig_feat,
                                 const float* __restrict__ prot_feat,
                                 const int* __restrict__ lig_batch,
                                 const float* __restrict__ t_emb,
                                 const float* __restrict__ W_lig, const float* __restrict__ b_lig,
                                 const float* __restrict__ W_prot, const float* __restrict__ b_prot,
                                 unsigned int* __restrict__ xb) {
    int node = blockIdx.x * 4 + (threadIdx.x >> 6);
    int h = threadIdx.x & 63;
    if (node >= NTOT) return;
    float acc;
    if (node < NLIG) {
        int b = lig_batch[node];
        acc = b_lig[h] + t_emb[b * H + h];
        #pragma unroll
        for (int k = 0; k < 15; k++)
            acc += lig_feat[node * 15 + k] * W_lig[k * H + h];
    } else {
        int p = node - NLIG;
        acc = b_prot[h];
        #pragma unroll
        for (int k = 0; k < 8; k++)
            acc += prot_feat[p * 8 + k] * W_prot[k * H + h];
    }
    float e0 = __shfl(acc, 2 * (h & 31));
    float e1 = __shfl(acc, 2 * (h & 31) + 1);
    if (h < 32)
        xb[node * 32 + h] = (unsigned int)f2bf(e0) | ((unsigned int)f2bf(e1) << 16);
}

// ---------------- bucketed CSR build ----------------
__global__ __launch_bounds__(1024) void bucket_hist_kernel(const int* __restrict__ edge_index,
                                                           unsigned int* __restrict__ bhist) {
    __shared__ unsigned int lh[NBUCK];
    int tid = threadIdx.x;
    for (int i = tid; i < NBUCK; i += 1024) lh[i] = 0;
    __syncthreads();
    int e0 = blockIdx.x * 8192;
    #pragma unroll
    for (int k = 0; k < 8; k++) {
        int d = edge_index[NEDGE + e0 + k * 1024 + tid];
        atomicAdd(&lh[d >> BSHIFT], 1);
    }
    __syncthreads();
    for (int i = tid; i < NBUCK; i += 1024)
        if (lh[i]) atomicAdd(&bhist[i], lh[i]);
}

__global__ __launch_bounds__(1024) void bucket_scan_kernel(const unsigned int* __restrict__ bhist,
                                                           unsigned int* __restrict__ bbase,
                                                           unsigned int* __restrict__ bcursor) {
    __shared__ unsigned int s[1024];
    int tid = threadIdx.x;
    unsigned int own = (tid < NBUCK) ? bhist[tid] : 0;
    s[tid] = own;
    __syncthreads();
    for (int d = 1; d < 1024; d <<= 1) {
        unsigned int v = (tid >= d) ? s[tid - d] : 0;
        __syncthreads();
        s[tid] += v;
        __syncthreads();
    }
    unsigned int excl = s[tid] - own;
    if (tid < NBUCK) { bbase[tid] = excl; bcursor[tid] = excl; }
    if (tid == 0) bbase[NBUCK] = NEDGE;
}

// fill: direct scatter of packed (src | dstlow<<18) into per-bucket contiguous runs.
// ranks within a block are dense (LDS cursors) -> each bucket's run is a
// contiguous ~14-word stretch -> write-combines in L2.
__global__ __launch_bounds__(1024) void bucket_fill_kernel(const int* __restrict__ edge_index,
                                                           unsigned int* __restrict__ bcursor,
                                                           unsigned int* __restrict__ bucketed) {
    __shared__ unsigned int lh[NBUCK];
    __shared__ unsigned int lcur[NBUCK];
    __shared__ unsigned int gb[NBUCK];
    int tid = threadIdx.x;
    for (int i = tid; i < NBUCK; i += 1024) lh[i] = 0;
    __syncthreads();
    int e0 = blockIdx.x * 8192;
    int src[8], dst[8];
    #pragma unroll
    for (int k = 0; k < 8; k++) {
        src[k] = edge_index[e0 + k * 1024 + tid];
        dst[k] = edge_index[NEDGE + e0 + k * 1024 + tid];
        atomicAdd(&lh[dst[k] >> BSHIFT], 1);
    }
    __syncthreads();
    if (tid < NBUCK) {
        gb[tid] = atomicAdd(&bcursor[tid], lh[tid]);
        lcur[tid] = 0;
    }
    __syncthreads();
    #pragma unroll
    for (int k = 0; k < 8; k++) {
        int b = dst[k] >> BSHIFT;
        unsigned int r = atomicAdd(&lcur[b], 1);
        bucketed[gb[b] + r] = (unsigned int)src[k] | ((unsigned int)(dst[k] & 255) << 18);
    }
}

__global__ __launch_bounds__(512) void bucket_csr_kernel(const unsigned int* __restrict__ bucketed,
                                                         const unsigned int* __restrict__ bbase,
                                                         int* __restrict__ off,
                                                         int* __restrict__ csr_src) {
    __shared__ unsigned int stage[4608];   // 18 KB packed
    __shared__ unsigned int csr_l[4608];   // 18 KB
    __shared__ unsigned int lh[256];
    __shared__ unsigned int lbeg[512];
    __shared__ unsigned int lcur[256];
    int b = blockIdx.x, tid = threadIdx.x;
    unsigned int base = bbase[b];
    int cnt = (int)(bbase[b + 1] - base);
    if (cnt > 4608) cnt = 4608;   // 16-sigma guard, never triggers
    for (int i = tid; i < 256; i += 512) lh[i] = 0;
    __syncthreads();
    for (int i = tid; i < cnt; i += 512) {
        unsigned int v = bucketed[base + i];
        stage[i] = v;
        atomicAdd(&lh[v >> 18], 1);
    }
    __syncthreads();
    unsigned int own = (tid < 256) ? lh[tid] : 0;
    lbeg[tid] = own;
    __syncthreads();
    for (int d = 1; d < 512; d <<= 1) {
        unsigned int v = (tid >= d) ? lbeg[tid - d] : 0;
        __syncthreads();
        lbeg[tid] += v;
        __syncthreads();
    }
    unsigned int excl = lbeg[tid] - own;
    __syncthreads();
    lbeg[tid] = excl;
    if (tid < 256) {
        lcur[tid] = excl;
        off[b * 256 + tid] = (int)(base + excl);
    }
    if (b == 0 && tid == 0) off[NTOT] = NEDGE;
    __syncthreads();
    for (int i = tid; i < cnt; i += 512) {
        unsigned int v = stage[i];
        unsigned int p = atomicAdd(&lcur[v >> 18], 1);
        csr_l[p] = v & 0x3ffffu;
    }
    __syncthreads();
    for (int i = tid; i < cnt; i += 512)
        csr_src[base + i] = (int)csr_l[i];
}

// ---------------- fused conv: node-per-slot gather + MFMA combine ----------------
// 512 threads = 8 waves, 128-node tile. Wave w owns rows [16w,16w+16).
// Gather: slot s=l>>3 = node (8 nodes concurrently), q=l&7 = feature quad.
// Each lane privately accumulates 8 features of its node; NO cross-lane reduce.
// j-loop unrolled x4 with masked id loads -> 4 gather rows in flight per lane
// (32 random 128B requests in flight per wave).
__global__ __launch_bounds__(512, 6) void conv_kernel(const int* __restrict__ off,
                                                      const int* __restrict__ csr,
                                                      const unsigned int* __restrict__ xb,
                                                      const unsigned short* __restrict__ wbuf,
                                                      const float* __restrict__ brel,
                                                      unsigned int* __restrict__ xob) {
    __shared__ unsigned int wlds[4096];            // 16 KB: rel frags [0,2048), root [2048,4096)
    __shared__ unsigned short agg_s[128 * 72];     // 18 KB, padded rows
    const int tid = threadIdx.x;
    const int w = tid >> 6, l = tid & 63;
    const int node0 = blockIdx.x * 128;
    const unsigned int* wsrc = (const unsigned int*)wbuf;
    #pragma unroll
    for (int i = 0; i < 8; i++) wlds[i * 512 + tid] = wsrc[i * 512 + tid];
    // (barrier for wlds deferred to just before the MFMA phase)

    const int s = l >> 3, q = l & 7;
    int offv = (l <= 16) ? off[node0 + w * 16 + l] : 0;

    #pragma unroll
    for (int g = 0; g < 2; g++) {
        int beg = __shfl(offv, g * 8 + s);
        int end = __shfl(offv, g * 8 + s + 1);
        int deg = end - beg;
        float a0 = 0.f, a1 = 0.f, a2 = 0.f, a3 = 0.f;
        float a4 = 0.f, a5 = 0.f, a6 = 0.f, a7 = 0.f;
        for (int j = 0; j < deg; j += 4) {
            // independent id loads (masked), then 4 independent gathers
            int n0 = csr[beg + j];
            int n1 = (j + 1 < deg) ? csr[beg + j + 1] : -1;
            int n2 = (j + 2 < deg) ? csr[beg + j + 2] : -1;
            int n3 = (j + 3 < deg) ? csr[beg + j + 3] : -1;
            {
                uint4 u = *(const uint4*)&xb[n0 * 32 + q * 4];
                a0 += bflo(u.x); a1 += bfhi(u.x);
                a2 += bflo(u.y); a3 += bfhi(u.y);
                a4 += bflo(u.z); a5 += bfhi(u.z);
                a6 += bflo(u.w); a7 += bfhi(u.w);
            }
            if (n1 >= 0) {
                uint4 u = *(const uint4*)&xb[n1 * 32 + q * 4];
                a0 += bflo(u.x); a1 += bfhi(u.x);
                a2 += bflo(u.y); a3 += bfhi(u.y);
                a4 += bflo(u.z); a5 += bfhi(u.z);
                a6 += bflo(u.w); a7 += bfhi(u.w);
            }
            if (n2 >= 0) {
                uint4 u = *(const uint4*)&xb[n2 * 32 + q * 4];
                a0 += bflo(u.x); a1 += bfhi(u.x);
                a2 += bflo(u.y); a3 += bfhi(u.y);
                a4 += bflo(u.z); a5 += bfhi(u.z);
                a6 += bflo(u.w); a7 += bfhi(u.w);
            }
            if (n3 >= 0) {
                uint4 u = *(const uint4*)&xb[n3 * 32 + q * 4];
                a0 += bflo(u.x); a1 += bfhi(u.x);
                a2 += bflo(u.y); a3 += bfhi(u.y);
                a4 += bflo(u.z); a5 += bfhi(u.z);
                a6 += bflo(u.w); a7 += bfhi(u.w);
            }
        }
        unsigned int p0 = (unsigned int)f2bf(a0) | ((unsigned int)f2bf(a1) << 16);
        unsigned int p1 = (unsigned int)f2bf(a2) | ((unsigned int)f2bf(a3) << 16);
        unsigned int p2 = (unsigned int)f2bf(a4) | ((unsigned int)f2bf(a5) << 16);
        unsigned int p3 = (unsigned int)f2bf(a6) | ((unsigned int)f2bf(a7) << 16);
        *(uint4*)&agg_s[(w * 16 + g * 8 + s) * 72 + q * 8] = make_uint4(p0, p1, p2, p3);
    }
    __syncthreads();   // wlds visible to all; agg rows are wave-local

    // ---- MFMA phase ----
    const int arow = w * 16 + (l & 15);
    const int g4 = 4 * (l >> 4);
    v4s ax[4];
    #pragma unroll
    for (int kt = 0; kt < 4; kt++)
        ax[kt] = *(const v4s*)&xb[(node0 + arow) * 32 + kt * 8 + (l >> 4) * 2];
    v4f acc[4];
    #pragma unroll
    for (int ct = 0; ct < 4; ct++) acc[ct] = (v4f){0.f, 0.f, 0.f, 0.f};
    #pragma unroll
    for (int kt = 0; kt < 4; kt++) {
        v4s a_agg = *(const v4s*)&agg_s[arow * 72 + kt * 16 + g4];
        #pragma unroll
        for (int ct = 0; ct < 4; ct++) {
            int f = kt * 4 + ct;
            v4s wr = *(const v4s*)&wlds[f * 128 + l * 2];
            v4s wo = *(const v4s*)&wlds[2048 + f * 128 + l * 2];
            acc[ct] = __builtin_amdgcn_mfma_f32_16x16x16bf16_1k(a_agg, wr, acc[ct], 0, 0, 0);
            acc[ct] = __builtin_amdgcn_mfma_f32_16x16x16bf16_1k(ax[kt], wo, acc[ct], 0, 0, 0);
        }
    }
    // ---- epilogue into agg tile (own rows) ----
    #pragma unroll
    for (int ct = 0; ct < 4; ct++) {
        float bv = brel[ct * 16 + (l & 15)];
        #pragma unroll
        for (int r = 0; r < 4; r++)
            agg_s[(w * 16 + g4 + r) * 72 + ct * 16 + (l & 15)] = f2bf(acc[ct][r] + bv);
    }
    __syncthreads();
    // coalesced writeout: 128 rows x 32 dwords
    {
        int row = tid >> 2, qq = tid & 3;
        const unsigned int* srcp = (const unsigned int*)&agg_s[row * 72 + qq * 16];
        uint4 v0 = *(const uint4*)(srcp);
        uint4 v1 = *(const uint4*)(srcp + 4);
        *(uint4*)&xob[(node0 + row) * 32 + qq * 8] = v0;
        *(uint4*)&xob[(node0 + row) * 32 + qq * 8 + 4] = v1;
    }
}

// ---------------- ligand pooling (bf16 x) ----------------
__global__ void pool_kernel(const unsigned int* __restrict__ xb,
                            const int* __restrict__ lig_batch,
                            float* __restrict__ pooled, float* __restrict__ cnt) {
    int node = blockIdx.x * 4 + (threadIdx.x >> 6);
    int h = threadIdx.x & 63;
    if (node >= NLIG) return;
    int b = lig_batch[node];
    unsigned int u = xb[node * 32 + (h >> 1)];
    float v = bf2f((unsigned short)((h & 1) ? (u >> 16) : (u & 0xffffu)));
    unsafeAtomicAdd(&pooled[b * H + h], v);
    if (h == 0) unsafeAtomicAdd(&cnt[b], 1.0f);
}

// ---------------- readout ----------------
__global__ void readout_kernel(const float* __restrict__ pooled, const float* __restrict__ cnt,
                               const float* __restrict__ Wro1, const float* __restrict__ bro1,
                               const float* __restrict__ Wro2, const float* __restrict__ bro2,
                               float* __restrict__ out) {
    __shared__ float pm[4][H];
    int w = threadIdx.x >> 6;
    int h = threadIdx.x & 63;
    int b = blockIdx.x * 4 + w;
    float c = fmaxf(cnt[b], 1.0f);
    pm[w][h] = pooled[b * H + h] / c;
    __syncthreads();
    float acc = bro1[h];
    #pragma unroll 8
    for (int k = 0; k < H; k++) acc += pm[w][k] * Wro1[k * H + h];
    float sig = 1.0f / (1.0f + expf(-acc));
    float s = acc * sig;
    float r = s * Wro2[h];
    #pragma unroll
    for (int off = 32; off; off >>= 1) r += __shfl_down(r, off);
    if (h == 0) out[b] = r + bro2[0];
}

extern "C" void kernel_launch(void* const* d_in, const int* in_sizes, int n_in,
                              void* d_out, int out_size, void* d_ws, size_t ws_size,
                              hipStream_t stream) {
    const float* lig_feat  = (const float*)d_in[1];
    const float* prot_feat = (const float*)d_in[3];
    const float* t         = (const float*)d_in[4];
    const int*   lig_batch = (const int*)d_in[5];
    const int*   edge_index= (const int*)d_in[7];
    const float* W_lig  = (const float*)d_in[8];
    const float* b_lig  = (const float*)d_in[9];
    const float* W_prot = (const float*)d_in[10];
    const float* b_prot = (const float*)d_in[11];
    const float* Wt1 = (const float*)d_in[12];
    const float* bt1 = (const float*)d_in[13];
    const float* Wt2 = (const float*)d_in[14];
    const float* bt2 = (const float*)d_in[15];
    const float* Wrel[3]  = {(const float*)d_in[16], (const float*)d_in[19], (const float*)d_in[22]};
    const float* brel[3]  = {(const float*)d_in[17], (const float*)d_in[20], (const float*)d_in[23]};
    const float* Wroot[3] = {(const float*)d_in[18], (const float*)d_in[21], (const float*)d_in[24]};
    const float* Wro1 = (const float*)d_in[25];
    const float* bro1 = (const float*)d_in[26];
    const float* Wro2 = (const float*)d_in[27];
    const float* bro2 = (const float*)d_in[28];
    float* out = (float*)d_out;

    char* ws = (char*)d_ws;
    int*            off_a   = (int*)(ws);                       // (NTOT+1) ints
    unsigned int*   bhist   = (unsigned int*)(ws + 655360);
    unsigned int*   bbase   = (unsigned int*)(ws + 659456);
    unsigned int*   bcursor = (unsigned int*)(ws + 665600);
    float*          t_emb   = (float*)(ws + 1376256);
    float*          pooled  = (float*)(ws + 1441792);
    float*          cnt     = (float*)(ws + 1507328);
    unsigned short* wbuf    = (unsigned short*)(ws + 1572864);  // 48 KB
    int*            csr_src = (int*)(ws + 2097152);             // 8 MB
    unsigned int*   bucketed= (unsigned int*)(ws + 10485760);   // 8 MB packed
    unsigned int*   xb0     = (unsigned int*)(ws + 27262976);   // 18 MB
    unsigned int*   xb1     = (unsigned int*)(ws + 46137344);   // 18 MB
    unsigned int*   xbs[2]  = {xb0, xb1};

    time_mlp_kernel<<<NB, H, 0, stream>>>(t, Wt1, bt1, Wt2, bt2, t_emb);
    wswz_kernel<<<dim3(16, 6), 256, 0, stream>>>(Wrel[0], Wroot[0], Wrel[1], Wroot[1],
                                                 Wrel[2], Wroot[2], wbuf);
    node_init_kernel<<<NTOT / 4, 256, 0, stream>>>(lig_feat, prot_feat, lig_batch, t_emb,
                                                   W_lig, b_lig, W_prot, b_prot, xb0);

    // ---- bucketed CSR build ----
    hipMemsetAsync(bhist, 0, NBUCK * sizeof(unsigned int), stream);
    bucket_hist_kernel<<<NEDGE / 8192, 1024, 0, stream>>>(edge_index, bhist);
    bucket_scan_kernel<<<1, 1024, 0, stream>>>(bhist, bbase, bcursor);
    bucket_fill_kernel<<<NEDGE / 8192, 1024, 0, stream>>>(edge_index, bcursor, bucketed);
    bucket_csr_kernel<<<NBUCK, 512, 0, stream>>>(bucketed, bbase, off_a, csr_src);

    // ---- 3 fused graph convs ----
    for (int lyr = 0; lyr < 3; lyr++) {
        unsigned int* cur = xbs[lyr & 1];
        unsigned int* nxt = xbs[(lyr + 1) & 1];
        conv_kernel<<<NTOT / 128, 512, 0, stream>>>(off_a, csr_src, cur,
                                                    wbuf + lyr * 8192, brel[lyr], nxt);
    }
    unsigned int* xfin = xbs[1];

    hipMemsetAsync(pooled, 0, (size_t)(NB * H + NB) * sizeof(float), stream);
    pool_kernel<<<NLIG / 4, 256, 0, stream>>>(xfin, lig_batch, pooled, cnt);
    readout_kernel<<<NB / 4, 256, 0, stream>>>(pooled, cnt, Wro1, bro1, Wro2, bro2, out);
}